// Round 1
// 1590.081 us; speedup vs baseline: 1.1186x; 1.1186x over previous
//
#include <hip/hip_runtime.h>

typedef unsigned short u16;
typedef __attribute__((ext_vector_type(8))) short vbf8;   // 8 bf16 = 4 VGPR
typedef __attribute__((ext_vector_type(4))) short vs4;    // 4 bf16 = 8 B
typedef __attribute__((ext_vector_type(4))) float vf4;    // MFMA acc

// ---------- bf16 <-> f32 (bitwise; RNE on pack) ----------
__device__ __forceinline__ float b2f(u16 u) {
  union { unsigned int i; float f; } v; v.i = ((unsigned int)u) << 16; return v.f;
}
__device__ __forceinline__ u16 f2b(float f) {
  union { float f; unsigned int i; } v; v.f = f;
  unsigned int r = v.i + 0x7fffu + ((v.i >> 16) & 1u);
  return (u16)(r >> 16);
}

// ---------- tiny cross-kernel state ------
__device__ float g_state[512];
#define GS_FEATWN 0      // 256
#define GS_FEATBL 256    // 128
#define GS_W3D    384    // 32
#define GS_BLEND  416    // 4
#define GS_ACCS   420    // 2

// ---------- transposed conv weight tables: (ic*9+t, oc), fp32 ----------
__device__ float g_wt[81936];
#define WT_WN1 0       // 27 x 32
#define WT_WN2 864     // 288 x 32 (unused by new k12m, kept for layout)
#define WT_WN3 10080   // 288 x 64
#define WT_WN4 28512   // 576 x 64
#define WT_BL1 65376   // 27 x 16
#define WT_BL2 65808   // 144 x 16 (unused by new k12m)
#define WT_BL3 68112   // 144 x 32
#define WT_BL4 72720   // 288 x 32

// ---------- MFMA-fragment-ordered bf16 conv2 weights ----------
// frag (t, nt): 64 lanes x 8 bf16; element (l, j) = W[oc=nt*16+(l&15)][ic=(l>>4)*8+j]
// WN: 9 taps x 2 ntiles = 18 frags @ 512 u16; BL: 9 frags (ic>=16 zero-padded)
__device__ __align__(16) u16 g_wfrag[13824];
#define WF_WN2 0
#define WF_BL2 9216

// ---------- output layout (fp32 elements) ----------
#define OUT_FUSED 12582912
#define OUT_TV    13014156
#define OUT_MN    13014157
#define OUT_W3D   13014158

// ---------- prep: transpose conv weights (O,I,3,3) -> (I*9, O) ----------
struct PrepDesc { const float* src; int O; int IKK; int dst; };
struct PrepArgs { PrepDesc d[8]; };

__global__ __launch_bounds__(256) void kprep(PrepArgs a) {
  PrepDesc t = a.d[blockIdx.x];
  int n = t.O * t.IKK;
  for (int e = threadIdx.x; e < n; e += 256) {
    int o = e / t.IKK, r = e - o * t.IKK;
    g_wt[t.dst + r * t.O + o] = t.src[e];
  }
}

// ---------- prep: pack conv2 weights into MFMA B-fragment order (bf16) ----------
__global__ __launch_bounds__(256) void kprep2(const float* __restrict__ wn2,
                                              const float* __restrict__ bl2) {
  int i = blockIdx.x * 256 + threadIdx.x;   // grid 54 * 256 = 13824 exact
  int fi = i >> 9, e = i & 511;
  int l = e >> 3, j = e & 7;
  int oc16 = l & 15, kk = (l >> 4) * 8 + j;
  if (fi < 18) {
    int t = fi >> 1, nt = fi & 1;
    g_wfrag[i] = f2b(wn2[((nt * 16 + oc16) * 32 + kk) * 9 + t]);
  } else {
    int t = fi - 18;
    g_wfrag[i] = (kk < 16) ? f2b(bl2[(oc16 * 16 + kk) * 9 + t]) : (u16)0;
  }
}

// ---------- fused conv1(stride1)+conv2(stride2), both relu, pad1 ----------
// conv1: fp32 VALU, all C1 oc per pixel, writes swizzled parity-split LDS.
// conv2: 9 tap-GEMMs on v_mfma_f32_16x16x32_bf16 (K = all C1 ic at once; BL's
//        K=16 zero-padded to 32 via zb + zeroed weight frags).
// h1p layout: [parity = x&1][y][hx = x>>1][C1 ic], 16B granule g stored at
// slot g ^ f(hx); f = (hx>>1)&3 for C1=32, (hx>>2)&1 for C1=16 -> A-frag
// ds_read_b128 lands on the wave64 b128 bank floor.
template<int C1, int C2, int NT, int NG>
__global__ __launch_bounds__(256) void k12m(
    const float* __restrict__ x, int w1o, const float* __restrict__ b1,
    const float* __restrict__ b2, int wfo, u16* __restrict__ h2)
{
  constexpr int FS = (NG == 4) ? 1 : 2;
  __shared__ __align__(16) u16 xs[3][35][36];           // 7,560 B
  __shared__ __align__(16) u16 h1p[2][33][17][C1];      // WN 71,808 B / BL 35,904 B
  __shared__ __align__(16) u16 zb[8];
  const int tid = threadIdx.x;
  const int lane = tid & 63, wv = tid >> 6;
  const int oy0 = blockIdx.y * 16, ox0 = blockIdx.x * 16;
  const int hy0 = 2 * oy0 - 1, hx0 = 2 * ox0 - 1;
  const float* xb = x + (size_t)blockIdx.z * 3145728u;
  u16* h2b = h2 + (size_t)blockIdx.z * (size_t)C2 * 262144u;

  if (tid < 8) zb[tid] = 0;
  for (int i = tid; i < 3675; i += 256) {
    int ic = i / 1225, rem = i - ic * 1225;
    int yy = rem / 35, xx = rem - yy * 35;
    int gy = hy0 - 1 + yy, gx = hx0 - 1 + xx;
    float v = 0.f;
    if ((unsigned)gy < 1024u && (unsigned)gx < 1024u)
      v = xb[ic * 1048576 + (gy << 10) + gx];
    xs[ic][yy][xx] = f2b(v);
  }
  __syncthreads();

  // ---- conv1: all C1 channels for the 33x33 halo ----
  for (int p = tid; p < 1089; p += 256) {
    const int py = p / 33, px = p - py * 33;
    const int par = px & 1, hx = px >> 1;
    u16* dst = &h1p[par][py][hx][0];
    const int gy = hy0 + py, gx = hx0 + px;
    if ((unsigned)gy < 1024u && (unsigned)gx < 1024u) {
      float xv[27];
      #pragma unroll
      for (int ic = 0; ic < 3; ic++)
        #pragma unroll
        for (int t = 0; t < 9; t++)
          xv[ic * 9 + t] = b2f(xs[ic][py + t / 3][px + t % 3]);
      float acc[C1];
      #pragma unroll
      for (int o = 0; o < C1; o++) acc[o] = b1[o];
      #pragma unroll
      for (int k = 0; k < 27; k++) {
        const float* wr = &g_wt[w1o + k * C1];
        #pragma unroll
        for (int o = 0; o < C1; o++) acc[o] = fmaf(xv[k], wr[o], acc[o]);
      }
      const int f = (hx >> FS) & (NG - 1);
      #pragma unroll
      for (int g = 0; g < NG; g++) {
        vbf8 pk;
        #pragma unroll
        for (int j = 0; j < 8; j++)
          pk[j] = (short)f2b(fmaxf(acc[g * 8 + j], 0.f));
        *(vbf8*)(dst + ((g ^ f) * 8)) = pk;
      }
    } else {
      vbf8 z = {0, 0, 0, 0, 0, 0, 0, 0};
      #pragma unroll
      for (int g = 0; g < NG; g++) *(vbf8*)(dst + g * 8) = z;
    }
  }
  __syncthreads();

  // ---- conv2: tap-decomposed GEMM on MFMA ----
  const int ocl = lane & 15;   // N index (B/D col)
  const int kg  = lane >> 4;   // K-group (A/B), px-group (D rows)

  vbf8 bw[9 * NT];
  {
    const u16* wfb = g_wfrag + wfo + lane * 8;
    #pragma unroll
    for (int i = 0; i < 9 * NT; i++)
      bw[i] = *(const vbf8*)(wfb + i * 512);
  }

  vf4 acc2[4][NT];
  #pragma unroll
  for (int nt = 0; nt < NT; nt++) {
    float bv = b2[nt * 16 + ocl];
    #pragma unroll
    for (int mt = 0; mt < 4; mt++) {
      vf4 c; c[0] = bv; c[1] = bv; c[2] = bv; c[3] = bv;
      acc2[mt][nt] = c;
    }
  }

  #pragma unroll
  for (int t = 0; t < 9; t++) {
    const int ty = t / 3, tx = t % 3;
    const int par = tx & 1;
    const int hx = (lane & 15) + (tx >> 1);   // A row = pixel px = lane&15
    const int f = (hx >> FS) & (NG - 1);
    #pragma unroll
    for (int mt = 0; mt < 4; mt++) {
      const int y = 2 * (wv * 4 + mt) + ty;
      const u16* ap;
      if constexpr (NG == 4) {
        ap = &h1p[par][y][hx][((kg ^ f) & 3) * 8];
      } else {
        ap = (kg < NG) ? &h1p[par][y][hx][((kg ^ f) & (NG - 1)) * 8] : zb;
      }
      vbf8 a = *(const vbf8*)ap;
      #pragma unroll
      for (int nt = 0; nt < NT; nt++)
        acc2[mt][nt] = __builtin_amdgcn_mfma_f32_16x16x32_bf16(
            a, bw[t * NT + nt], acc2[mt][nt], 0, 0, 0);
    }
  }

  // ---- epilogue: relu + bf16, D layout col=lane&15(oc), row=(lane>>4)*4+j(px)
  #pragma unroll
  for (int mt = 0; mt < 4; mt++) {
    const int oy = oy0 + wv * 4 + mt;
    const int oxb = ox0 + kg * 4;
    #pragma unroll
    for (int nt = 0; nt < NT; nt++) {
      vs4 q;
      #pragma unroll
      for (int j = 0; j < 4; j++)
        q[j] = (short)f2b(fmaxf(acc2[mt][nt][j], 0.f));
      *(vs4*)(h2b + (size_t)(nt * 16 + ocl) * 262144u + (oy << 9) + oxb) = q;
    }
  }
}

// ---------- stride-2 conv, relu, pad1 (conv3/conv4), bf16 in/out ----------
template<int CIN, int COUT, int OCB>
__global__ __launch_bounds__(256) void k34(
    const u16* __restrict__ in, int wo, const float* __restrict__ bia,
    u16* __restrict__ out, int HIN)
{
  constexpr int OCG = COUT / OCB;
  __shared__ u16 hs[8][33][34];        // 17,952 B
  __shared__ float wchunk[72 * OCB];
  const int HO = HIN >> 1;
  const int tid = threadIdx.x;
  const int py = tid >> 4, px = tid & 15;
  const int zb2 = blockIdx.z / OCG;
  const int og = blockIdx.z - zb2 * OCG;
  const int oc0 = og * OCB;
  const int oy0 = blockIdx.y * 16, ox0 = blockIdx.x * 16;
  const int iy0 = 2 * oy0 - 1, ix0 = 2 * ox0 - 1;
  const u16* ib = in + (size_t)zb2 * (size_t)CIN * HIN * HIN;
  u16* ob = out + (size_t)zb2 * (size_t)COUT * HO * HO
                + (size_t)oc0 * HO * HO + (oy0 + py) * HO + (ox0 + px);

  float acc[OCB];
  #pragma unroll
  for (int o = 0; o < OCB; o++) acc[o] = bia[oc0 + o];

  for (int ch = 0; ch < CIN; ch += 8) {
    for (int i = tid; i < 8712; i += 256) {
      int ic = i / 1089, rem = i - ic * 1089;
      int yy = rem / 33, xx = rem - yy * 33;
      int gy = iy0 + yy, gx = ix0 + xx;
      u16 v = 0;
      if ((unsigned)gy < (unsigned)HIN && (unsigned)gx < (unsigned)HIN)
        v = ib[(ch + ic) * HIN * HIN + gy * HIN + gx];
      hs[ic][yy][xx] = v;
    }
    for (int i = tid; i < 72 * OCB; i += 256) {
      int r = i / OCB, o = i & (OCB - 1);
      wchunk[i] = g_wt[wo + (ch * 9 + r) * COUT + oc0 + o];
    }
    __syncthreads();

    #pragma unroll
    for (int ic = 0; ic < 8; ic++) {
      #pragma unroll
      for (int t = 0; t < 9; t++) {
        float v = b2f(hs[ic][2 * py + t / 3][2 * px + t % 3]);
        const float* wr = &wchunk[(ic * 9 + t) * OCB];
        #pragma unroll
        for (int o = 0; o < OCB; o++)
          acc[o] = fmaf(v, wr[o], acc[o]);
      }
    }
    __syncthreads();
  }

  #pragma unroll
  for (int o = 0; o < OCB; o++)
    ob[o * HO * HO] = f2b(fmaxf(acc[o], 0.f));
}

// ---------- global mean over 128x128 per channel, 2 batches ----------
__global__ __launch_bounds__(256) void kmean(const u16* __restrict__ in,
                                             int C, int gofs) {
  const int c = blockIdx.x, z = blockIdx.y;
  const u16* p = in + ((size_t)z * C + c) * 16384;
  float s = 0.f;
  for (int i = threadIdx.x; i < 16384; i += 256) s += b2f(p[i]);
  __shared__ float red[256];
  red[threadIdx.x] = s; __syncthreads();
  for (int st = 128; st > 0; st >>= 1) {
    if (threadIdx.x < st) red[threadIdx.x] += red[threadIdx.x + st];
    __syncthreads();
  }
  if (threadIdx.x == 0) g_state[gofs + z * C + c] = red[0] * (1.f / 16384.f);
}

// ---------- FC head ----------
template<int CF, int NOUT, bool SIG>
__global__ __launch_bounds__(256) void khead(
    const float* __restrict__ fw1, const float* __restrict__ fb1,
    const float* __restrict__ fw2, const float* __restrict__ fb2,
    int feato, int outo, float* out_f)
{
  __shared__ float fc1[4 * CF];
  const int tid = threadIdx.x;
  if (tid < 4 * CF) {
    int b = tid / CF, o = tid - b * CF;
    float s = fb1[o];
    for (int i = 0; i < CF; i++)
      s = fmaf(g_state[feato + b * CF + i], fw1[o * CF + i], s);
    fc1[tid] = fmaxf(s, 0.f);
  }
  __syncthreads();
  if (tid < 4 * NOUT) {
    int b = tid / NOUT, n = tid - b * NOUT;
    float s = fb2[n];
    for (int i = 0; i < CF; i++)
      s = fmaf(fc1[b * CF + i], fw2[n * CF + i], s);
    if (SIG) s = 1.f / (1.f + expf(-s));
    g_state[outo + b * NOUT + n] = s;
    if (out_f) out_f[b * NOUT + n] = s;
  }
}

// ---------- fused LUT = clip(w3d @ luts + identity, 0,1) ----------
__global__ __launch_bounds__(256) void kfuse(
    const float* __restrict__ luts, float* __restrict__ outF)
{
  if (blockIdx.x == 0 && threadIdx.x == 0) {
    g_state[GS_ACCS] = 0.f; g_state[GS_ACCS + 1] = 0.f;
  }
  int idx = blockIdx.x * 256 + threadIdx.x;
  if (idx >= 431244) return;
  int n = idx / 107811, m = idx - n * 107811;
  int c = m / 35937, q = m - c * 35937;
  int bq = q / 1089, r2 = q - bq * 1089;
  int gq = r2 / 33, rq = r2 - gq * 33;
  int id = (c == 0) ? rq : (c == 1) ? gq : bq;
  float s = (float)id * (1.f / 32.f);
  #pragma unroll
  for (int k = 0; k < 8; k++)
    s = fmaf(g_state[GS_W3D + n * 8 + k], luts[k * 107811 + m], s);
  s = fminf(fmaxf(s, 0.f), 1.f);
  outF[idx] = s;
}

// ---------- TV + monotonicity reductions over fused ----------
__global__ __launch_bounds__(256) void ktv(const float* __restrict__ f) {
  const int Nr = 418176;
  float tv = 0.f, mn = 0.f;
  for (int e = blockIdx.x * 256 + threadIdx.x; e < 3 * Nr; e += gridDim.x * 256) {
    int dir = e / Nr, j = e - dir * Nr;
    int i, stride; float w;
    if (dir == 0) {
      int r = j & 31; int t = j >> 5;
      int g = t % 33; t /= 33;
      i = t * 1089 + g * 33 + r; stride = 1;
      w = (r == 0 || r == 31) ? 2.f : 1.f;
    } else if (dir == 1) {
      int r = j % 33; int t = j / 33; int g = t & 31; t >>= 5;
      i = t * 1089 + g * 33 + r; stride = 33;
      w = (g == 0 || g == 31) ? 2.f : 1.f;
    } else {
      int r = j % 33; int t = j / 33; int g = t % 33; t /= 33;
      int bb = t & 31; t >>= 5;
      i = (t * 33 + bb) * 1089 + g * 33 + r; stride = 1089;
      w = (bb == 0 || bb == 31) ? 2.f : 1.f;
    }
    float d = f[i] - f[i + stride];
    tv = fmaf(d * d, w, tv);
    mn += fmaxf(d, 0.f);
  }
  __shared__ float r1[256], r2[256];
  r1[threadIdx.x] = tv; r2[threadIdx.x] = mn; __syncthreads();
  for (int st = 128; st > 0; st >>= 1) {
    if (threadIdx.x < st) { r1[threadIdx.x] += r1[threadIdx.x + st];
                            r2[threadIdx.x] += r2[threadIdx.x + st]; }
    __syncthreads();
  }
  if (threadIdx.x == 0) {
    atomicAdd(&g_state[GS_ACCS], r1[0]);
    atomicAdd(&g_state[GS_ACCS + 1], r2[0]);
  }
}

// ---------- trilinear apply + blend + clip; finalize tv/mn ----------
__global__ __launch_bounds__(256) void kapply(
    const float* __restrict__ x, const float* __restrict__ F,
    float* __restrict__ out)
{
  int p = blockIdx.x * 256 + threadIdx.x;
  if (p == 0) {
    out[OUT_TV] = g_state[GS_ACCS] * (1.f / 418176.f);
    out[OUT_MN] = g_state[GS_ACCS + 1] * (1.f / 418176.f);
  }
  int b = p >> 20, yx = p & 1048575;
  size_t base = (size_t)b * 3145728u + yx;
  float xr = x[base];
  float xg = x[base + 1048576];
  float xb = x[base + 2097152];
  float a = g_state[GS_BLEND + b];
  float sr = fminf(fmaxf(xr, 0.f), 1.f) * 32.f;
  float sg = fminf(fmaxf(xg, 0.f), 1.f) * 32.f;
  float sb = fminf(fmaxf(xb, 0.f), 1.f) * 32.f;
  int ir = min((int)sr, 31), ig = min((int)sg, 31), ib = min((int)sb, 31);
  float fr = sr - ir, fg = sg - ig, fb = sb - ib;
  const float* Fb = F + (size_t)b * 107811u + ib * 1089 + ig * 33 + ir;
  #pragma unroll
  for (int c = 0; c < 3; c++) {
    const float* Fc = Fb + c * 35937;
    float v000 = Fc[0],    v001 = Fc[1];
    float v010 = Fc[33],   v011 = Fc[34];
    float v100 = Fc[1089], v101 = Fc[1090];
    float v110 = Fc[1122], v111 = Fc[1123];
    float c00 = v000 + fr * (v001 - v000);
    float c01 = v010 + fr * (v011 - v010);
    float c10 = v100 + fr * (v101 - v100);
    float c11 = v110 + fr * (v111 - v110);
    float c0 = c00 + fg * (c01 - c00);
    float c1 = c10 + fg * (c11 - c10);
    float v  = c0 + fb * (c1 - c0);
    float xv = (c == 0) ? xr : (c == 1) ? xg : xb;
    float o = fminf(fmaxf((1.f - a) * xv + a * v, 0.f), 1.f);
    out[(size_t)(b * 3 + c) * 1048576u + yx] = o;
  }
}

extern "C" void kernel_launch(void* const* d_in, const int* in_sizes, int n_in,
                              void* d_out, int out_size, void* d_ws, size_t ws_size,
                              hipStream_t stream)
{
  (void)in_sizes; (void)n_in; (void)out_size;
  const float* x    = (const float*)d_in[0];
  const float* luts = (const float*)d_in[1];
  const float* wn_b1 = (const float*)d_in[3];
  const float* wn_b2 = (const float*)d_in[5];
  const float* wn_b3 = (const float*)d_in[7];
  const float* wn_b4 = (const float*)d_in[9];
  const float* wn_fw1 = (const float*)d_in[10], *wn_fb1 = (const float*)d_in[11];
  const float* wn_fw2 = (const float*)d_in[12], *wn_fb2 = (const float*)d_in[13];
  const float* bl_b1 = (const float*)d_in[15];
  const float* bl_b2 = (const float*)d_in[17];
  const float* bl_b3 = (const float*)d_in[19];
  const float* bl_b4 = (const float*)d_in[21];
  const float* bl_fw1 = (const float*)d_in[22], *bl_fb1 = (const float*)d_in[23];
  const float* bl_fw2 = (const float*)d_in[24], *bl_fb2 = (const float*)d_in[25];
  float* out = (float*)d_out;

  u16 *scrA, *scrB;
  if (ws_size >= 50331648u) {
    scrA = (u16*)d_ws;
    scrB = (u16*)d_ws + 16777216;
  } else {
    scrA = (u16*)out;
    scrB = (u16*)out + 16777216;
  }

  PrepArgs pa;
  const float* src[8] = {(const float*)d_in[2], (const float*)d_in[4],
                         (const float*)d_in[6], (const float*)d_in[8],
                         (const float*)d_in[14], (const float*)d_in[16],
                         (const float*)d_in[18], (const float*)d_in[20]};
  const int O[8]   = {32, 32, 64, 64, 16, 16, 32, 32};
  const int IKK[8] = {27, 288, 288, 576, 27, 144, 144, 288};
  const int DST[8] = {WT_WN1, WT_WN2, WT_WN3, WT_WN4,
                      WT_BL1, WT_BL2, WT_BL3, WT_BL4};
  for (int t = 0; t < 8; t++) {
    pa.d[t].src = src[t]; pa.d[t].O = O[t];
    pa.d[t].IKK = IKK[t]; pa.d[t].dst = DST[t];
  }
  kprep<<<dim3(8), 256, 0, stream>>>(pa);
  kprep2<<<dim3(54), 256, 0, stream>>>((const float*)d_in[4], (const float*)d_in[16]);

  // ---- weight-net (WN), 2 batches per pass ----
  for (int b0 = 0; b0 < 4; b0 += 2) {
    const float* xb = x + (size_t)b0 * 3145728u;
    k12m<32,32,2,4><<<dim3(32,32,2), 256, 0, stream>>>(xb, WT_WN1, wn_b1, wn_b2, WF_WN2, scrA);
    k34<32,64,32><<<dim3(16,16,4), 256, 0, stream>>>(scrA, WT_WN3, wn_b3, scrB, 512);
    k34<64,64,16><<<dim3(8,8,8),   256, 0, stream>>>(scrB, WT_WN4, wn_b4, scrA, 256);
    kmean<<<dim3(64,2), 256, 0, stream>>>(scrA, 64, GS_FEATWN + b0 * 64);
  }
  khead<64,8,false><<<1,256,0,stream>>>(wn_fw1, wn_fb1, wn_fw2, wn_fb2,
                                        GS_FEATWN, GS_W3D, out + OUT_W3D);

  // ---- blend-net (BL), 2 batches per pass ----
  for (int b0 = 0; b0 < 4; b0 += 2) {
    const float* xb = x + (size_t)b0 * 3145728u;
    k12m<16,16,1,2><<<dim3(32,32,2), 256, 0, stream>>>(xb, WT_BL1, bl_b1, bl_b2, WF_BL2, scrA);
    k34<16,32,32><<<dim3(16,16,2), 256, 0, stream>>>(scrA, WT_BL3, bl_b3, scrB, 512);
    k34<32,32,16><<<dim3(8,8,4),   256, 0, stream>>>(scrB, WT_BL4, bl_b4, scrA, 256);
    kmean<<<dim3(32,2), 256, 0, stream>>>(scrA, 32, GS_FEATBL + b0 * 32);
  }
  khead<32,1,true ><<<1,256,0,stream>>>(bl_fw1, bl_fb1, bl_fw2, bl_fb2,
                                        GS_FEATBL, GS_BLEND, (float*)nullptr);

  // ---- LUT fuse, TV, final apply ----
  kfuse<<<1685, 256, 0, stream>>>(luts, out + OUT_FUSED);
  ktv<<<512, 256, 0, stream>>>(out + OUT_FUSED);
  kapply<<<16384, 256, 0, stream>>>(x, out + OUT_FUSED, out);
}

// Round 2
// 772.834 us; speedup vs baseline: 2.3015x; 2.0575x over previous
//
#include <hip/hip_runtime.h>

typedef unsigned short u16;
typedef unsigned int u32;
typedef __attribute__((ext_vector_type(8))) short vbf8;   // 8 bf16 = 4 VGPR
typedef __attribute__((ext_vector_type(4))) short vs4;    // 4 bf16 = 8 B
typedef __attribute__((ext_vector_type(4))) float vf4;    // MFMA acc

// ---------- bf16 <-> f32 (bitwise; RNE on pack) ----------
__device__ __forceinline__ float b2f(u16 u) {
  union { unsigned int i; float f; } v; v.i = ((unsigned int)u) << 16; return v.f;
}
__device__ __forceinline__ u16 f2b(float f) {
  union { float f; unsigned int i; } v; v.f = f;
  unsigned int r = v.i + 0x7fffu + ((v.i >> 16) & 1u);
  return (u16)(r >> 16);
}
__device__ __forceinline__ u16 f2h(float f) {
  union { _Float16 h; u16 s; } cv; cv.h = (_Float16)f; return cv.s;
}
__device__ __forceinline__ float h2f(u16 u) {
  union { _Float16 h; u16 s; } cv; cv.s = u; return (float)cv.h;
}

// ---------- tiny cross-kernel state ------
__device__ float g_state[512];
#define GS_FEATWN 0      // 256
#define GS_FEATBL 256    // 128
#define GS_W3D    384    // 32
#define GS_BLEND  416    // 4
#define GS_ACCS   420    // 2

// ---------- transposed conv1 weight tables: (ic*9+t, oc), fp32 ----------
__device__ float g_wt[2048];
#define WT_WN1 0       // 27 x 32
#define WT_BL1 1024    // 27 x 16

// ---------- MFMA-fragment-ordered bf16 conv weights ----------
// frag (kc,t,nt): 64 lanes x 8 bf16; elem (l,j) = W[oc=nt*16+(l&15)][ic=kc*32+(l>>4)*8+j][t]
// frag index within layer = (kc*9 + t)*NTF + nt ; ic >= I zero-padded.
__device__ __align__(16) u16 g_wfrag[87552];
#define WF_WN2 0       // NTF=2 KC=1 : 18 frags
#define WF_BL2 9216    // NTF=1 KC=1 :  9
#define WF_WN3 13824   // NTF=4 KC=1 : 36
#define WF_WN4 32256   // NTF=4 KC=2 : 72
#define WF_BL3 69120   // NTF=2 KC=1 : 18 (I=16 zero-pad)
#define WF_BL4 78336   // NTF=2 KC=1 : 18

// ---------- output layout (fp32 elements) ----------
#define OUT_FUSED 12582912
#define OUT_TV    13014156
#define OUT_MN    13014157
#define OUT_W3D   13014158

// ---------- prep: transpose conv1 weights (O,I,3,3) -> (I*9, O) ----------
struct PrepDesc { const float* src; int O; int IKK; int dst; };
struct PrepArgs { PrepDesc d[2]; };

__global__ __launch_bounds__(256) void kprep(PrepArgs a) {
  PrepDesc t = a.d[blockIdx.x];
  int n = t.O * t.IKK;
  for (int e = threadIdx.x; e < n; e += 256) {
    int o = e / t.IKK, r = e - o * t.IKK;
    g_wt[t.dst + r * t.O + o] = t.src[e];
  }
}

// ---------- prep: pack conv2..4 weights into MFMA B-fragment order ----------
struct P2Args { const float* w[6]; int I[6]; int ntf[6]; int base[6]; };

__global__ __launch_bounds__(256) void kprep2(P2Args a) {
  int i = blockIdx.x * 256 + threadIdx.x;   // grid 342*256 = 87552 exact
  int l = 0;
  #pragma unroll
  for (int k = 1; k < 6; k++) if (i >= a.base[k]) l = k;
  int e2 = i - a.base[l];
  int frag = e2 >> 9, e = e2 & 511;
  int ll = e >> 3, j = e & 7;
  int NTF = a.ntf[l];
  int kc = frag / (9 * NTF);
  int r = frag - kc * 9 * NTF;
  int t = r / NTF, nt = r - t * NTF;
  int I = a.I[l];
  int oc = nt * 16 + (ll & 15);
  int ic = kc * 32 + (ll >> 4) * 8 + j;
  g_wfrag[i] = (ic < I) ? f2b(a.w[l][(oc * I + ic) * 9 + t]) : (u16)0;
}

// ---------- fused conv1(stride1)+conv2(stride2), both relu, pad1 ----------
// conv1: fp32 VALU -> swizzled parity-split LDS (bf16).
// conv2: 9 tap-GEMMs on v_mfma_f32_16x16x32_bf16. Output NHWC [z][512][512][C2].
template<int C1, int C2, int NT, int NG>
__global__ __launch_bounds__(256) void k12m(
    const float* __restrict__ x, int w1o, const float* __restrict__ b1,
    const float* __restrict__ b2, int wfo, u16* __restrict__ h2)
{
  constexpr int FS = (NG == 4) ? 1 : 2;
  __shared__ __align__(16) u16 xs[3][35][36];
  __shared__ __align__(16) u16 h1p[2][33][17][C1];
  __shared__ __align__(16) u16 zbuf[8];
  const int tid = threadIdx.x;
  const int lane = tid & 63, wv = tid >> 6;
  const int oy0 = blockIdx.y * 16, ox0 = blockIdx.x * 16;
  const int hy0 = 2 * oy0 - 1, hx0 = 2 * ox0 - 1;
  const float* xb = x + (size_t)blockIdx.z * 3145728u;
  u16* h2b = h2 + (size_t)blockIdx.z * 262144u * (size_t)C2;

  if (tid < 8) zbuf[tid] = 0;
  for (int i = tid; i < 3675; i += 256) {
    int ic = i / 1225, rem = i - ic * 1225;
    int yy = rem / 35, xx = rem - yy * 35;
    int gy = hy0 - 1 + yy, gx = hx0 - 1 + xx;
    float v = 0.f;
    if ((unsigned)gy < 1024u && (unsigned)gx < 1024u)
      v = xb[ic * 1048576 + (gy << 10) + gx];
    xs[ic][yy][xx] = f2b(v);
  }
  __syncthreads();

  // ---- conv1 ----
  for (int p = tid; p < 1089; p += 256) {
    const int py = p / 33, px = p - py * 33;
    const int par = px & 1, hx = px >> 1;
    u16* dst = &h1p[par][py][hx][0];
    const int gy = hy0 + py, gx = hx0 + px;
    if ((unsigned)gy < 1024u && (unsigned)gx < 1024u) {
      float xv[27];
      #pragma unroll
      for (int ic = 0; ic < 3; ic++)
        #pragma unroll
        for (int t = 0; t < 9; t++)
          xv[ic * 9 + t] = b2f(xs[ic][py + t / 3][px + t % 3]);
      float acc[C1];
      #pragma unroll
      for (int o = 0; o < C1; o++) acc[o] = b1[o];
      #pragma unroll
      for (int k = 0; k < 27; k++) {
        const float* wr = &g_wt[w1o + k * C1];
        #pragma unroll
        for (int o = 0; o < C1; o++) acc[o] = fmaf(xv[k], wr[o], acc[o]);
      }
      const int f = (hx >> FS) & (NG - 1);
      #pragma unroll
      for (int g = 0; g < NG; g++) {
        vbf8 pk;
        #pragma unroll
        for (int j = 0; j < 8; j++)
          pk[j] = (short)f2b(fmaxf(acc[g * 8 + j], 0.f));
        *(vbf8*)(dst + ((g ^ f) * 8)) = pk;
      }
    } else {
      vbf8 z = {0, 0, 0, 0, 0, 0, 0, 0};
      #pragma unroll
      for (int g = 0; g < NG; g++) *(vbf8*)(dst + g * 8) = z;
    }
  }
  __syncthreads();

  // ---- conv2: tap-decomposed GEMM ----
  const int ocl = lane & 15;
  const int kg  = lane >> 4;

  vbf8 bw[9 * NT];
  {
    const u16* wfb = g_wfrag + wfo + lane * 8;
    #pragma unroll
    for (int i = 0; i < 9 * NT; i++)
      bw[i] = *(const vbf8*)(wfb + i * 512);
  }

  vf4 acc2[4][NT];
  #pragma unroll
  for (int nt = 0; nt < NT; nt++) {
    float bv = b2[nt * 16 + ocl];
    #pragma unroll
    for (int mt = 0; mt < 4; mt++) {
      vf4 c; c[0] = bv; c[1] = bv; c[2] = bv; c[3] = bv;
      acc2[mt][nt] = c;
    }
  }

  #pragma unroll
  for (int t = 0; t < 9; t++) {
    const int ty = t / 3, tx = t % 3;
    const int par = tx & 1;
    const int hx = (lane & 15) + (tx >> 1);
    const int f = (hx >> FS) & (NG - 1);
    #pragma unroll
    for (int mt = 0; mt < 4; mt++) {
      const int y = 2 * (wv * 4 + mt) + ty;
      const u16* ap;
      if constexpr (NG == 4) {
        ap = &h1p[par][y][hx][((kg ^ f) & 3) * 8];
      } else {
        ap = (kg < NG) ? &h1p[par][y][hx][((kg ^ f) & (NG - 1)) * 8] : zbuf;
      }
      vbf8 a = *(const vbf8*)ap;
      #pragma unroll
      for (int nt = 0; nt < NT; nt++)
        acc2[mt][nt] = __builtin_amdgcn_mfma_f32_16x16x32_bf16(
            a, bw[t * NT + nt], acc2[mt][nt], 0, 0, 0);
    }
  }

  // ---- epilogue: NHWC [z][512][512][C2] ----
  #pragma unroll
  for (int mt = 0; mt < 4; mt++) {
    const int oy = oy0 + wv * 4 + mt;
    #pragma unroll
    for (int nt = 0; nt < NT; nt++) {
      #pragma unroll
      for (int j = 0; j < 4; j++) {
        const int ox = ox0 + kg * 4 + j;
        h2b[((size_t)(oy << 9) + ox) * C2 + nt * 16 + ocl] =
            f2b(fmaxf(acc2[mt][nt][j], 0.f));
      }
    }
  }
}

// ---------- stride-2 conv on MFMA (conv3/conv4), NHWC in ----------
// grid (HO/16, HO/16, 2*OCG). Out NHWC if !PLANAR else NCHW (for kmean).
template<int CIN, int COUT, int NT, int NG, int KC, bool PLANAR>
__global__ __launch_bounds__(256) void k34m(
    const u16* __restrict__ in, const float* __restrict__ bia,
    int wfo, u16* __restrict__ out, int HIN)
{
  constexpr int FS = (NG == 4) ? 1 : 2;
  constexpr int NTF = COUT / 16;
  constexpr int OCG = COUT / (NT * 16);
  __shared__ __align__(16) u16 h1p[2][33][17][NG * 8];
  __shared__ __align__(16) u16 zbuf[8];
  const int HO = HIN >> 1;
  const int tid = threadIdx.x;
  const int lane = tid & 63, wv = tid >> 6;
  const int zb2 = blockIdx.z / OCG;
  const int og = blockIdx.z - zb2 * OCG;
  const int oy0 = blockIdx.y * 16, ox0 = blockIdx.x * 16;
  const int iy0 = 2 * oy0 - 1, ix0 = 2 * ox0 - 1;
  const u16* inb = in + (size_t)zb2 * (size_t)HIN * HIN * CIN;

  if (tid < 8) zbuf[tid] = 0;

  const int ocl = lane & 15;
  const int kg  = lane >> 4;

  vf4 acc2[4][NT];
  #pragma unroll
  for (int nt = 0; nt < NT; nt++) {
    float bv = bia[og * NT * 16 + nt * 16 + ocl];
    #pragma unroll
    for (int mt = 0; mt < 4; mt++) {
      vf4 c; c[0] = bv; c[1] = bv; c[2] = bv; c[3] = bv;
      acc2[mt][nt] = c;
    }
  }

  vbf8 bw[9 * NT];

  for (int kc = 0; kc < KC; kc++) {
    if (kc) __syncthreads();
    // stage input chunk (32 ic) into swizzled parity-split LDS
    for (int i = tid; i < 33 * 33 * NG; i += 256) {
      int g = i & (NG - 1);
      int pp = i / NG;
      int yy = pp / 33, xx = pp - yy * 33;
      int gy = iy0 + yy, gx = ix0 + xx;
      vbf8 v = {0, 0, 0, 0, 0, 0, 0, 0};
      if ((unsigned)gy < (unsigned)HIN && (unsigned)gx < (unsigned)HIN)
        v = *(const vbf8*)(inb + (size_t)(gy * HIN + gx) * CIN + kc * 32 + g * 8);
      const int par = xx & 1, hx = xx >> 1;
      const int f = (hx >> FS) & (NG - 1);
      *(vbf8*)(&h1p[par][yy][hx][(g ^ f) * 8]) = v;
    }
    // chunk weights
    {
      const u16* wfb = g_wfrag + wfo + lane * 8;
      #pragma unroll
      for (int t = 0; t < 9; t++)
        #pragma unroll
        for (int nt = 0; nt < NT; nt++)
          bw[t * NT + nt] =
              *(const vbf8*)(wfb + (size_t)((kc * 9 + t) * NTF + og * NT + nt) * 512);
    }
    __syncthreads();

    #pragma unroll
    for (int t = 0; t < 9; t++) {
      const int ty = t / 3, tx = t % 3;
      const int par = tx & 1;
      const int hx = (lane & 15) + (tx >> 1);
      const int f = (hx >> FS) & (NG - 1);
      #pragma unroll
      for (int mt = 0; mt < 4; mt++) {
        const int y = 2 * (wv * 4 + mt) + ty;
        const u16* ap;
        if constexpr (NG == 4) {
          ap = &h1p[par][y][hx][((kg ^ f) & 3) * 8];
        } else {
          ap = (kg < NG) ? &h1p[par][y][hx][((kg ^ f) & (NG - 1)) * 8] : zbuf;
        }
        vbf8 a = *(const vbf8*)ap;
        #pragma unroll
        for (int nt = 0; nt < NT; nt++)
          acc2[mt][nt] = __builtin_amdgcn_mfma_f32_16x16x32_bf16(
              a, bw[t * NT + nt], acc2[mt][nt], 0, 0, 0);
      }
    }
  }

  // epilogue
  #pragma unroll
  for (int mt = 0; mt < 4; mt++) {
    const int oy = oy0 + wv * 4 + mt;
    #pragma unroll
    for (int nt = 0; nt < NT; nt++) {
      const int oc = og * NT * 16 + nt * 16 + ocl;
      if constexpr (PLANAR) {
        vs4 qq;
        #pragma unroll
        for (int j = 0; j < 4; j++)
          qq[j] = (short)f2b(fmaxf(acc2[mt][nt][j], 0.f));
        *(vs4*)(out + (size_t)zb2 * COUT * HO * HO + (size_t)oc * HO * HO
                + oy * HO + ox0 + kg * 4) = qq;
      } else {
        #pragma unroll
        for (int j = 0; j < 4; j++) {
          const int ox = ox0 + kg * 4 + j;
          out[((size_t)zb2 * HO * HO + (size_t)(oy * HO + ox)) * COUT + oc] =
              f2b(fmaxf(acc2[mt][nt][j], 0.f));
        }
      }
    }
  }
}

// ---------- global mean over 128x128 per channel (planar in), 2 batches ----------
__global__ __launch_bounds__(256) void kmean(const u16* __restrict__ in,
                                             int C, int gofs) {
  const int c = blockIdx.x, z = blockIdx.y;
  const u16* p = in + ((size_t)z * C + c) * 16384;
  float s = 0.f;
  for (int i = threadIdx.x; i < 16384; i += 256) s += b2f(p[i]);
  __shared__ float red[256];
  red[threadIdx.x] = s; __syncthreads();
  for (int st = 128; st > 0; st >>= 1) {
    if (threadIdx.x < st) red[threadIdx.x] += red[threadIdx.x + st];
    __syncthreads();
  }
  if (threadIdx.x == 0) g_state[gofs + z * C + c] = red[0] * (1.f / 16384.f);
}

// ---------- FC head ----------
template<int CF, int NOUT, bool SIG>
__global__ __launch_bounds__(256) void khead(
    const float* __restrict__ fw1, const float* __restrict__ fb1,
    const float* __restrict__ fw2, const float* __restrict__ fb2,
    int feato, int outo, float* out_f)
{
  __shared__ float fc1[4 * CF];
  const int tid = threadIdx.x;
  if (tid < 4 * CF) {
    int b = tid / CF, o = tid - b * CF;
    float s = fb1[o];
    for (int i = 0; i < CF; i++)
      s = fmaf(g_state[feato + b * CF + i], fw1[o * CF + i], s);
    fc1[tid] = fmaxf(s, 0.f);
  }
  __syncthreads();
  if (tid < 4 * NOUT) {
    int b = tid / NOUT, n = tid - b * NOUT;
    float s = fb2[n];
    for (int i = 0; i < CF; i++)
      s = fmaf(fc1[b * CF + i], fw2[n * CF + i], s);
    if (SIG) s = 1.f / (1.f + expf(-s));
    g_state[outo + b * NOUT + n] = s;
    if (out_f) out_f[b * NOUT + n] = s;
  }
}

// ---------- fused LUT = clip(w3d @ luts + identity, 0,1); also fp16 AoS copy ----------
__global__ __launch_bounds__(256) void kfuse(
    const float* __restrict__ luts, float* __restrict__ outF,
    u16* __restrict__ Fa)
{
  if (blockIdx.x == 0 && threadIdx.x == 0) {
    g_state[GS_ACCS] = 0.f; g_state[GS_ACCS + 1] = 0.f;
  }
  int idx = blockIdx.x * 256 + threadIdx.x;
  if (idx >= 431244) return;
  int n = idx / 107811, m = idx - n * 107811;
  int c = m / 35937, q = m - c * 35937;
  int bq = q / 1089, r2 = q - bq * 1089;
  int gq = r2 / 33, rq = r2 - gq * 33;
  int id = (c == 0) ? rq : (c == 1) ? gq : bq;
  float s = (float)id * (1.f / 32.f);
  #pragma unroll
  for (int k = 0; k < 8; k++)
    s = fmaf(g_state[GS_W3D + n * 8 + k], luts[k * 107811 + m], s);
  s = fminf(fmaxf(s, 0.f), 1.f);
  outF[idx] = s;
  if (Fa) Fa[(n * 35937 + q) * 4 + c] = f2h(s);
}

// ---------- TV + monotonicity reductions over fused ----------
__global__ __launch_bounds__(256) void ktv(const float* __restrict__ f) {
  const int Nr = 418176;
  float tv = 0.f, mn = 0.f;
  for (int e = blockIdx.x * 256 + threadIdx.x; e < 3 * Nr; e += gridDim.x * 256) {
    int dir = e / Nr, j = e - dir * Nr;
    int i, stride; float w;
    if (dir == 0) {
      int r = j & 31; int t = j >> 5;
      int g = t % 33; t /= 33;
      i = t * 1089 + g * 33 + r; stride = 1;
      w = (r == 0 || r == 31) ? 2.f : 1.f;
    } else if (dir == 1) {
      int r = j % 33; int t = j / 33; int g = t & 31; t >>= 5;
      i = t * 1089 + g * 33 + r; stride = 33;
      w = (g == 0 || g == 31) ? 2.f : 1.f;
    } else {
      int r = j % 33; int t = j / 33; int g = t % 33; t /= 33;
      int bb = t & 31; t >>= 5;
      i = (t * 33 + bb) * 1089 + g * 33 + r; stride = 1089;
      w = (bb == 0 || bb == 31) ? 2.f : 1.f;
    }
    float d = f[i] - f[i + stride];
    tv = fmaf(d * d, w, tv);
    mn += fmaxf(d, 0.f);
  }
  __shared__ float r1[256], r2[256];
  r1[threadIdx.x] = tv; r2[threadIdx.x] = mn; __syncthreads();
  for (int st = 128; st > 0; st >>= 1) {
    if (threadIdx.x < st) { r1[threadIdx.x] += r1[threadIdx.x + st];
                            r2[threadIdx.x] += r2[threadIdx.x + st]; }
    __syncthreads();
  }
  if (threadIdx.x == 0) {
    atomicAdd(&g_state[GS_ACCS], r1[0]);
    atomicAdd(&g_state[GS_ACCS + 1], r2[0]);
  }
}

// ---------- trilinear apply + blend + clip; finalize tv/mn ----------
__global__ __launch_bounds__(256) void kapply(
    const float* __restrict__ x, const float* __restrict__ F,
    const u16* __restrict__ Fa, float* __restrict__ out)
{
  int p = blockIdx.x * 256 + threadIdx.x;
  if (p == 0) {
    out[OUT_TV] = g_state[GS_ACCS] * (1.f / 418176.f);
    out[OUT_MN] = g_state[GS_ACCS + 1] * (1.f / 418176.f);
  }
  int b = p >> 20, yx = p & 1048575;
  size_t base = (size_t)b * 3145728u + yx;
  float xr = x[base];
  float xg = x[base + 1048576];
  float xb = x[base + 2097152];
  float a = g_state[GS_BLEND + b];
  float sr = fminf(fmaxf(xr, 0.f), 1.f) * 32.f;
  float sg = fminf(fmaxf(xg, 0.f), 1.f) * 32.f;
  float sb = fminf(fmaxf(xb, 0.f), 1.f) * 32.f;
  int ir = min((int)sr, 31), ig = min((int)sg, 31), ib = min((int)sb, 31);
  float fr = sr - ir, fg = sg - ig, fb = sb - ib;

  if (Fa) {
    // AoS fp16: cell = 4 halves {R,G,B,pad} = 2 uints; load r-pairs as 2x uint2
    const int cb = b * 35937 + ib * 1089 + ig * 33 + ir;
    const u32* Fu = (const u32*)Fa;
    u32 q[4][4];
    #pragma unroll
    for (int db = 0; db < 2; db++)
      #pragma unroll
      for (int dg = 0; dg < 2; dg++) {
        const u32* c0 = Fu + (size_t)(cb + db * 1089 + dg * 33) * 2;
        q[db * 2 + dg][0] = c0[0]; q[db * 2 + dg][1] = c0[1];
        q[db * 2 + dg][2] = c0[2]; q[db * 2 + dg][3] = c0[3];
      }
    #pragma unroll
    for (int c = 0; c < 3; c++) {
      const int k = c >> 1, sh = (c & 1) * 16;
      float v000 = h2f((u16)(q[0][k]     >> sh));
      float v001 = h2f((u16)(q[0][2 + k] >> sh));
      float v010 = h2f((u16)(q[1][k]     >> sh));
      float v011 = h2f((u16)(q[1][2 + k] >> sh));
      float v100 = h2f((u16)(q[2][k]     >> sh));
      float v101 = h2f((u16)(q[2][2 + k] >> sh));
      float v110 = h2f((u16)(q[3][k]     >> sh));
      float v111 = h2f((u16)(q[3][2 + k] >> sh));
      float c00 = v000 + fr * (v001 - v000);
      float c01 = v010 + fr * (v011 - v010);
      float c10 = v100 + fr * (v101 - v100);
      float c11 = v110 + fr * (v111 - v110);
      float c0 = c00 + fg * (c01 - c00);
      float c1 = c10 + fg * (c11 - c10);
      float v  = c0 + fb * (c1 - c0);
      float xv = (c == 0) ? xr : (c == 1) ? xg : xb;
      float o = fminf(fmaxf((1.f - a) * xv + a * v, 0.f), 1.f);
      out[(size_t)(b * 3 + c) * 1048576u + yx] = o;
    }
  } else {
    const float* Fb = F + (size_t)b * 107811u + ib * 1089 + ig * 33 + ir;
    #pragma unroll
    for (int c = 0; c < 3; c++) {
      const float* Fc = Fb + c * 35937;
      float v000 = Fc[0],    v001 = Fc[1];
      float v010 = Fc[33],   v011 = Fc[34];
      float v100 = Fc[1089], v101 = Fc[1090];
      float v110 = Fc[1122], v111 = Fc[1123];
      float c00 = v000 + fr * (v001 - v000);
      float c01 = v010 + fr * (v011 - v010);
      float c10 = v100 + fr * (v101 - v100);
      float c11 = v110 + fr * (v111 - v110);
      float c0 = c00 + fg * (c01 - c00);
      float c1 = c10 + fg * (c11 - c10);
      float v  = c0 + fb * (c1 - c0);
      float xv = (c == 0) ? xr : (c == 1) ? xg : xb;
      float o = fminf(fmaxf((1.f - a) * xv + a * v, 0.f), 1.f);
      out[(size_t)(b * 3 + c) * 1048576u + yx] = o;
    }
  }
}

extern "C" void kernel_launch(void* const* d_in, const int* in_sizes, int n_in,
                              void* d_out, int out_size, void* d_ws, size_t ws_size,
                              hipStream_t stream)
{
  (void)in_sizes; (void)n_in; (void)out_size;
  const float* x    = (const float*)d_in[0];
  const float* luts = (const float*)d_in[1];
  const float* wn_b1 = (const float*)d_in[3];
  const float* wn_b2 = (const float*)d_in[5];
  const float* wn_b3 = (const float*)d_in[7];
  const float* wn_b4 = (const float*)d_in[9];
  const float* wn_fw1 = (const float*)d_in[10], *wn_fb1 = (const float*)d_in[11];
  const float* wn_fw2 = (const float*)d_in[12], *wn_fb2 = (const float*)d_in[13];
  const float* bl_b1 = (const float*)d_in[15];
  const float* bl_b3 = (const float*)d_in[19];
  const float* bl_b4 = (const float*)d_in[21];
  const float* bl_fw1 = (const float*)d_in[22], *bl_fb1 = (const float*)d_in[23];
  const float* bl_fw2 = (const float*)d_in[24], *bl_fb2 = (const float*)d_in[25];
  float* out = (float*)d_out;

  // bf16 scratch for a 2-batch pair: scrA (<=33.6MB) + scrB (<=16.8MB).
  // After the conv nets are done, the scratch is dead; the fp16 AoS LUT
  // copy (1.15 MB) overlays scrA when d_ws is available.
  u16 *scrA, *scrB, *Fa;
  if (ws_size >= 50331648u) {
    scrA = (u16*)d_ws;
    scrB = (u16*)d_ws + 16777216;
    Fa = (u16*)d_ws;
  } else {
    scrA = (u16*)out;
    scrB = (u16*)out + 16777216;
    Fa = nullptr;                 // SoA fallback path in kapply
  }

  PrepArgs pa;
  pa.d[0].src = (const float*)d_in[2];  pa.d[0].O = 32; pa.d[0].IKK = 27; pa.d[0].dst = WT_WN1;
  pa.d[1].src = (const float*)d_in[14]; pa.d[1].O = 16; pa.d[1].IKK = 27; pa.d[1].dst = WT_BL1;
  kprep<<<dim3(2), 256, 0, stream>>>(pa);

  P2Args p2;
  const float* wsrc[6] = {(const float*)d_in[4],  (const float*)d_in[16],
                          (const float*)d_in[6],  (const float*)d_in[8],
                          (const float*)d_in[18], (const float*)d_in[20]};
  const int pI[6]   = {32, 16, 32, 64, 16, 32};
  const int pNTF[6] = {2, 1, 4, 4, 2, 2};
  const int pB[6]   = {WF_WN2, WF_BL2, WF_WN3, WF_WN4, WF_BL3, WF_BL4};
  for (int l = 0; l < 6; l++) { p2.w[l] = wsrc[l]; p2.I[l] = pI[l];
                                p2.ntf[l] = pNTF[l]; p2.base[l] = pB[l]; }
  kprep2<<<dim3(342), 256, 0, stream>>>(p2);

  // ---- weight-net (WN), 2 batches per pass ----
  for (int b0 = 0; b0 < 4; b0 += 2) {
    const float* xb = x + (size_t)b0 * 3145728u;
    k12m<32,32,2,4><<<dim3(32,32,2), 256, 0, stream>>>(xb, WT_WN1, wn_b1, wn_b2, WF_WN2, scrA);
    k34m<32,64,2,4,1,false><<<dim3(16,16,4), 256, 0, stream>>>(scrA, wn_b3, WF_WN3, scrB, 512);
    k34m<64,64,2,4,2,true ><<<dim3(8,8,4),   256, 0, stream>>>(scrB, wn_b4, WF_WN4, scrA, 256);
    kmean<<<dim3(64,2), 256, 0, stream>>>(scrA, 64, GS_FEATWN + b0 * 64);
  }
  khead<64,8,false><<<1,256,0,stream>>>(wn_fw1, wn_fb1, wn_fw2, wn_fb2,
                                        GS_FEATWN, GS_W3D, out + OUT_W3D);

  // ---- blend-net (BL), 2 batches per pass ----
  for (int b0 = 0; b0 < 4; b0 += 2) {
    const float* xb = x + (size_t)b0 * 3145728u;
    k12m<16,16,1,2><<<dim3(32,32,2), 256, 0, stream>>>(xb, WT_BL1, bl_b1, nullptr ? nullptr : (const float*)d_in[17], WF_BL2, scrA);
    k34m<16,32,2,2,1,false><<<dim3(16,16,2), 256, 0, stream>>>(scrA, bl_b3, WF_BL3, scrB, 512);
    k34m<32,32,2,4,1,true ><<<dim3(8,8,2),   256, 0, stream>>>(scrB, bl_b4, WF_BL4, scrA, 256);
    kmean<<<dim3(32,2), 256, 0, stream>>>(scrA, 32, GS_FEATBL + b0 * 32);
  }
  khead<32,1,true ><<<1,256,0,stream>>>(bl_fw1, bl_fb1, bl_fw2, bl_fb2,
                                        GS_FEATBL, GS_BLEND, (float*)nullptr);

  // ---- LUT fuse (+fp16 AoS), TV, final apply ----
  kfuse<<<1685, 256, 0, stream>>>(luts, out + OUT_FUSED, Fa);
  ktv<<<512, 256, 0, stream>>>(out + OUT_FUSED);
  kapply<<<16384, 256, 0, stream>>>(x, out + OUT_FUSED, Fa, out);
}

// Round 3
// 644.954 us; speedup vs baseline: 2.7579x; 1.1983x over previous
//
#include <hip/hip_runtime.h>

typedef unsigned short u16;
typedef unsigned int u32;
typedef __attribute__((ext_vector_type(8))) short vbf8;   // 8 bf16 = 4 VGPR
typedef __attribute__((ext_vector_type(4))) short vs4;    // 4 bf16 = 8 B
typedef __attribute__((ext_vector_type(4))) float vf4;    // MFMA acc

// ---------- bf16 <-> f32 (bitwise; RNE on pack) ----------
__device__ __forceinline__ float b2f(u16 u) {
  union { unsigned int i; float f; } v; v.i = ((unsigned int)u) << 16; return v.f;
}
__device__ __forceinline__ u16 f2b(float f) {
  union { float f; unsigned int i; } v; v.f = f;
  unsigned int r = v.i + 0x7fffu + ((v.i >> 16) & 1u);
  return (u16)(r >> 16);
}
__device__ __forceinline__ u16 f2h(float f) {
  union { _Float16 h; u16 s; } cv; cv.h = (_Float16)f; return cv.s;
}
__device__ __forceinline__ float h2f(u16 u) {
  union { _Float16 h; u16 s; } cv; cv.s = u; return (float)cv.h;
}

// ---------- tiny cross-kernel state ------
__device__ float g_state[512];
#define GS_FEATWN 0      // 256
#define GS_FEATBL 256    // 128
#define GS_W3D    384    // 32
#define GS_BLEND  416    // 4
#define GS_ACCS   420    // 2

// ---------- MFMA-fragment-ordered bf16 conv weights ----------
// conv2..4 frag (kc,t,nt): 64 lanes x 8 bf16;
//   elem (l,j) = W[oc=nt*16+(l&15)][ic=kc*32+(l>>4)*8+j][t]; idx = (kc*9+t)*NTF+nt
// conv1 frag (mt): elem (l,j) = W[oc=mt*16+(l&15)][k=(l>>4)*8+j], k=ic*9+t, k>=27 pad0
__device__ __align__(16) u16 g_wfrag[89088];
#define WF_WN2 0       // NTF=2 KC=1 : 18 frags
#define WF_BL2 9216    // NTF=1 KC=1 :  9
#define WF_WN3 13824   // NTF=4 KC=1 : 36
#define WF_WN4 32256   // NTF=4 KC=2 : 72
#define WF_BL3 69120   // NTF=2 KC=1 : 18 (I=16 zero-pad)
#define WF_BL4 78336   // NTF=2 KC=1 : 18
#define WF_WN1 87552   // conv1: 2 frags
#define WF_BL1 88576   // conv1: 1 frag

// ---------- output layout (fp32 elements) ----------
#define OUT_FUSED 12582912
#define OUT_TV    13014156
#define OUT_MN    13014157
#define OUT_W3D   13014158

// ---------- prep: pack all conv weights into MFMA fragment order ----------
struct P2Args { const float* w[8]; int I[8]; int ntf[8]; int base[8]; };

__global__ __launch_bounds__(256) void kprep2(P2Args a) {
  int i = blockIdx.x * 256 + threadIdx.x;   // grid 348*256 = 89088 exact
  int l = 0;
  #pragma unroll
  for (int k = 1; k < 8; k++) if (i >= a.base[k]) l = k;
  int e2 = i - a.base[l];
  int frag = e2 >> 9, e = e2 & 511;
  int ll = e >> 3, j = e & 7;
  if (l < 6) {
    int NTF = a.ntf[l];
    int kc = frag / (9 * NTF);
    int r = frag - kc * 9 * NTF;
    int t = r / NTF, nt = r - t * NTF;
    int I = a.I[l];
    int oc = nt * 16 + (ll & 15);
    int ic = kc * 32 + (ll >> 4) * 8 + j;
    g_wfrag[i] = (ic < I) ? f2b(a.w[l][(oc * I + ic) * 9 + t]) : (u16)0;
  } else {
    int k = (ll >> 4) * 8 + j;                  // k = ic*9 + tap
    int oc = frag * 16 + (ll & 15);
    g_wfrag[i] = (k < 27) ? f2b(a.w[l][oc * 27 + k]) : (u16)0;
  }
}

// ---------- fused conv1(stride1)+conv2(stride2), both relu, pad1 ----------
// conv1: K=27(->32) GEMM on MFMA, A=weights (rows=oc), B=x-patches (cols=pixels).
//   D cols = pixels -> lane writes a 4-oc quad per mtile via ds_write_b64
//   straight into the swizzled AoS h1p layout (no shuffles).
// conv2: 9 tap-GEMMs on MFMA. Output NHWC [z][512][512][C2].
template<int C1, int C2, int NT, int NG>
__global__ __launch_bounds__(256) void k12m(
    const float* __restrict__ x, int wf1o, const float* __restrict__ b1,
    const float* __restrict__ b2, int wfo, u16* __restrict__ h2)
{
  constexpr int FS = (NG == 4) ? 1 : 2;
  constexpr int MT1 = C1 / 16;
  __shared__ __align__(16) u16 xs[3][35][36];
  __shared__ __align__(16) u16 h1p[2][33][17][C1];
  __shared__ __align__(16) u16 zbuf[8];
  const int tid = threadIdx.x;
  const int lane = tid & 63, wv = tid >> 6;
  const int ocl = lane & 15;   // D col index (pixel in conv1, oc in conv2)
  const int kg  = lane >> 4;   // K-group
  const int oy0 = blockIdx.y * 16, ox0 = blockIdx.x * 16;
  const int hy0 = 2 * oy0 - 1, hx0 = 2 * ox0 - 1;
  const float* xb = x + (size_t)blockIdx.z * 3145728u;
  u16* h2b = h2 + (size_t)blockIdx.z * 262144u * (size_t)C2;

  if (tid < 8) zbuf[tid] = 0;
  for (int i = tid; i < 3675; i += 256) {
    int ic = i / 1225, rem = i - ic * 1225;
    int yy = rem / 35, xx = rem - yy * 35;
    int gy = hy0 - 1 + yy, gx = hx0 - 1 + xx;
    float v = 0.f;
    if ((unsigned)gy < 1024u && (unsigned)gx < 1024u)
      v = xb[ic * 1048576 + (gy << 10) + gx];
    xs[ic][yy][xx] = f2b(v);
  }

  // conv1 weight frags + biases (registers, uniform per lane)
  vbf8 wa1[MT1];
  float bias1[MT1][4];
  {
    const u16* wfb = g_wfrag + wf1o + lane * 8;
    #pragma unroll
    for (int mt = 0; mt < MT1; mt++) {
      wa1[mt] = *(const vbf8*)(wfb + mt * 512);
      #pragma unroll
      for (int j = 0; j < 4; j++)
        bias1[mt][j] = b1[mt * 16 + kg * 4 + j];
    }
  }
  __syncthreads();

  // ---- conv1: 69 pixel-tiles of 16 over the 33x33 halo ----
  for (int pt = wv; pt < 69; pt += 4) {
    const int p = pt * 16 + ocl;
    const bool ok = (p < 1089);
    const int pc = ok ? p : 1088;
    const int py = pc / 33, px = pc - py * 33;
    vbf8 bfrag;
    #pragma unroll
    for (int j = 0; j < 8; j++) {
      const int k = kg * 8 + j;
      u16 v = 0;
      if (k < 27) {
        const int ic = k / 9, tt = k - ic * 9;
        v = xs[ic][py + tt / 3][px + tt % 3];
      }
      bfrag[j] = (short)v;
    }
    const int par = px & 1, hx = px >> 1;
    const int f = (hx >> FS) & (NG - 1);
    #pragma unroll
    for (int mt = 0; mt < MT1; mt++) {
      vf4 z = {0.f, 0.f, 0.f, 0.f};
      vf4 d = __builtin_amdgcn_mfma_f32_16x16x32_bf16(wa1[mt], bfrag, z, 0, 0, 0);
      if (ok) {
        vs4 pk;
        #pragma unroll
        for (int j = 0; j < 4; j++)
          pk[j] = (short)f2b(fmaxf(d[j] + bias1[mt][j], 0.f));
        const int q = kg + 4 * mt;        // oc-quad index
        *(vs4*)(&h1p[par][py][hx][((q >> 1) ^ f) * 8 + (q & 1) * 4]) = pk;
      }
    }
  }
  __syncthreads();

  // ---- conv2: tap-decomposed GEMM ----
  vbf8 bw[9 * NT];
  {
    const u16* wfb = g_wfrag + wfo + lane * 8;
    #pragma unroll
    for (int i = 0; i < 9 * NT; i++)
      bw[i] = *(const vbf8*)(wfb + i * 512);
  }

  vf4 acc2[4][NT];
  #pragma unroll
  for (int nt = 0; nt < NT; nt++) {
    float bv = b2[nt * 16 + ocl];
    #pragma unroll
    for (int mt = 0; mt < 4; mt++) {
      vf4 c; c[0] = bv; c[1] = bv; c[2] = bv; c[3] = bv;
      acc2[mt][nt] = c;
    }
  }

  #pragma unroll
  for (int t = 0; t < 9; t++) {
    const int ty = t / 3, tx = t % 3;
    const int par = tx & 1;
    const int hx = (lane & 15) + (tx >> 1);
    const int f = (hx >> FS) & (NG - 1);
    #pragma unroll
    for (int mt = 0; mt < 4; mt++) {
      const int y = 2 * (wv * 4 + mt) + ty;
      const u16* ap;
      if constexpr (NG == 4) {
        ap = &h1p[par][y][hx][((kg ^ f) & 3) * 8];
      } else {
        ap = (kg < NG) ? &h1p[par][y][hx][((kg ^ f) & (NG - 1)) * 8] : zbuf;
      }
      vbf8 a = *(const vbf8*)ap;
      #pragma unroll
      for (int nt = 0; nt < NT; nt++)
        acc2[mt][nt] = __builtin_amdgcn_mfma_f32_16x16x32_bf16(
            a, bw[t * NT + nt], acc2[mt][nt], 0, 0, 0);
    }
  }

  // ---- epilogue: NHWC [z][512][512][C2] ----
  #pragma unroll
  for (int mt = 0; mt < 4; mt++) {
    const int oy = oy0 + wv * 4 + mt;
    #pragma unroll
    for (int nt = 0; nt < NT; nt++) {
      #pragma unroll
      for (int j = 0; j < 4; j++) {
        const int ox = ox0 + kg * 4 + j;
        h2b[((size_t)(oy << 9) + ox) * C2 + nt * 16 + ocl] =
            f2b(fmaxf(acc2[mt][nt][j], 0.f));
      }
    }
  }
}

// ---------- stride-2 conv on MFMA (conv3/conv4), NHWC in ----------
// grid (HO/16, HO/16, 2*OCG). Out NHWC if !PLANAR else NCHW (for kmean).
template<int CIN, int COUT, int NT, int NG, int KC, bool PLANAR>
__global__ __launch_bounds__(256) void k34m(
    const u16* __restrict__ in, const float* __restrict__ bia,
    int wfo, u16* __restrict__ out, int HIN)
{
  constexpr int FS = (NG == 4) ? 1 : 2;
  constexpr int NTF = COUT / 16;
  constexpr int OCG = COUT / (NT * 16);
  __shared__ __align__(16) u16 h1p[2][33][17][NG * 8];
  __shared__ __align__(16) u16 zbuf[8];
  const int HO = HIN >> 1;
  const int tid = threadIdx.x;
  const int lane = tid & 63, wv = tid >> 6;
  const int zb2 = blockIdx.z / OCG;
  const int og = blockIdx.z - zb2 * OCG;
  const int oy0 = blockIdx.y * 16, ox0 = blockIdx.x * 16;
  const int iy0 = 2 * oy0 - 1, ix0 = 2 * ox0 - 1;
  const u16* inb = in + (size_t)zb2 * (size_t)HIN * HIN * CIN;

  if (tid < 8) zbuf[tid] = 0;

  const int ocl = lane & 15;
  const int kg  = lane >> 4;

  vf4 acc2[4][NT];
  #pragma unroll
  for (int nt = 0; nt < NT; nt++) {
    float bv = bia[og * NT * 16 + nt * 16 + ocl];
    #pragma unroll
    for (int mt = 0; mt < 4; mt++) {
      vf4 c; c[0] = bv; c[1] = bv; c[2] = bv; c[3] = bv;
      acc2[mt][nt] = c;
    }
  }

  vbf8 bw[9 * NT];

  for (int kc = 0; kc < KC; kc++) {
    if (kc) __syncthreads();
    // stage input chunk (32 ic) into swizzled parity-split LDS
    for (int i = tid; i < 33 * 33 * NG; i += 256) {
      int g = i & (NG - 1);
      int pp = i / NG;
      int yy = pp / 33, xx = pp - yy * 33;
      int gy = iy0 + yy, gx = ix0 + xx;
      vbf8 v = {0, 0, 0, 0, 0, 0, 0, 0};
      if ((unsigned)gy < (unsigned)HIN && (unsigned)gx < (unsigned)HIN)
        v = *(const vbf8*)(inb + (size_t)(gy * HIN + gx) * CIN + kc * 32 + g * 8);
      const int par = xx & 1, hx = xx >> 1;
      const int f = (hx >> FS) & (NG - 1);
      *(vbf8*)(&h1p[par][yy][hx][(g ^ f) * 8]) = v;
    }
    // chunk weights
    {
      const u16* wfb = g_wfrag + wfo + lane * 8;
      #pragma unroll
      for (int t = 0; t < 9; t++)
        #pragma unroll
        for (int nt = 0; nt < NT; nt++)
          bw[t * NT + nt] =
              *(const vbf8*)(wfb + (size_t)((kc * 9 + t) * NTF + og * NT + nt) * 512);
    }
    __syncthreads();

    #pragma unroll
    for (int t = 0; t < 9; t++) {
      const int ty = t / 3, tx = t % 3;
      const int par = tx & 1;
      const int hx = (lane & 15) + (tx >> 1);
      const int f = (hx >> FS) & (NG - 1);
      #pragma unroll
      for (int mt = 0; mt < 4; mt++) {
        const int y = 2 * (wv * 4 + mt) + ty;
        const u16* ap;
        if constexpr (NG == 4) {
          ap = &h1p[par][y][hx][((kg ^ f) & 3) * 8];
        } else {
          ap = (kg < NG) ? &h1p[par][y][hx][((kg ^ f) & (NG - 1)) * 8] : zbuf;
        }
        vbf8 a = *(const vbf8*)ap;
        #pragma unroll
        for (int nt = 0; nt < NT; nt++)
          acc2[mt][nt] = __builtin_amdgcn_mfma_f32_16x16x32_bf16(
              a, bw[t * NT + nt], acc2[mt][nt], 0, 0, 0);
      }
    }
  }

  // epilogue
  #pragma unroll
  for (int mt = 0; mt < 4; mt++) {
    const int oy = oy0 + wv * 4 + mt;
    #pragma unroll
    for (int nt = 0; nt < NT; nt++) {
      const int oc = og * NT * 16 + nt * 16 + ocl;
      if constexpr (PLANAR) {
        vs4 qq;
        #pragma unroll
        for (int j = 0; j < 4; j++)
          qq[j] = (short)f2b(fmaxf(acc2[mt][nt][j], 0.f));
        *(vs4*)(out + (size_t)zb2 * COUT * HO * HO + (size_t)oc * HO * HO
                + oy * HO + ox0 + kg * 4) = qq;
      } else {
        #pragma unroll
        for (int j = 0; j < 4; j++) {
          const int ox = ox0 + kg * 4 + j;
          out[((size_t)zb2 * HO * HO + (size_t)(oy * HO + ox)) * COUT + oc] =
              f2b(fmaxf(acc2[mt][nt][j], 0.f));
        }
      }
    }
  }
}

// ---------- global mean over 128x128 per channel (planar in), 2 batches ----------
__global__ __launch_bounds__(256) void kmean(const u16* __restrict__ in,
                                             int C, int gofs) {
  const int c = blockIdx.x, z = blockIdx.y;
  const u16* p = in + ((size_t)z * C + c) * 16384;
  float s = 0.f;
  for (int i = threadIdx.x; i < 16384; i += 256) s += b2f(p[i]);
  __shared__ float red[256];
  red[threadIdx.x] = s; __syncthreads();
  for (int st = 128; st > 0; st >>= 1) {
    if (threadIdx.x < st) red[threadIdx.x] += red[threadIdx.x + st];
    __syncthreads();
  }
  if (threadIdx.x == 0) g_state[gofs + z * C + c] = red[0] * (1.f / 16384.f);
}

// ---------- FC head ----------
template<int CF, int NOUT, bool SIG>
__global__ __launch_bounds__(256) void khead(
    const float* __restrict__ fw1, const float* __restrict__ fb1,
    const float* __restrict__ fw2, const float* __restrict__ fb2,
    int feato, int outo, float* out_f)
{
  __shared__ float fc1[4 * CF];
  const int tid = threadIdx.x;
  if (tid < 4 * CF) {
    int b = tid / CF, o = tid - b * CF;
    float s = fb1[o];
    for (int i = 0; i < CF; i++)
      s = fmaf(g_state[feato + b * CF + i], fw1[o * CF + i], s);
    fc1[tid] = fmaxf(s, 0.f);
  }
  __syncthreads();
  if (tid < 4 * NOUT) {
    int b = tid / NOUT, n = tid - b * NOUT;
    float s = fb2[n];
    for (int i = 0; i < CF; i++)
      s = fmaf(fc1[b * CF + i], fw2[n * CF + i], s);
    if (SIG) s = 1.f / (1.f + expf(-s));
    g_state[outo + b * NOUT + n] = s;
    if (out_f) out_f[b * NOUT + n] = s;
  }
}

// ---------- fused LUT = clip(w3d @ luts + identity, 0,1); also fp16 AoS copy ----------
__global__ __launch_bounds__(256) void kfuse(
    const float* __restrict__ luts, float* __restrict__ outF,
    u16* __restrict__ Fa)
{
  if (blockIdx.x == 0 && threadIdx.x == 0) {
    g_state[GS_ACCS] = 0.f; g_state[GS_ACCS + 1] = 0.f;
  }
  int idx = blockIdx.x * 256 + threadIdx.x;
  if (idx >= 431244) return;
  int n = idx / 107811, m = idx - n * 107811;
  int c = m / 35937, q = m - c * 35937;
  int bq = q / 1089, r2 = q - bq * 1089;
  int gq = r2 / 33, rq = r2 - gq * 33;
  int id = (c == 0) ? rq : (c == 1) ? gq : bq;
  float s = (float)id * (1.f / 32.f);
  #pragma unroll
  for (int k = 0; k < 8; k++)
    s = fmaf(g_state[GS_W3D + n * 8 + k], luts[k * 107811 + m], s);
  s = fminf(fmaxf(s, 0.f), 1.f);
  outF[idx] = s;
  if (Fa) Fa[(n * 35937 + q) * 4 + c] = f2h(s);
}

// ---------- TV + monotonicity reductions over fused ----------
__global__ __launch_bounds__(256) void ktv(const float* __restrict__ f) {
  const int Nr = 418176;
  float tv = 0.f, mn = 0.f;
  for (int e = blockIdx.x * 256 + threadIdx.x; e < 3 * Nr; e += gridDim.x * 256) {
    int dir = e / Nr, j = e - dir * Nr;
    int i, stride; float w;
    if (dir == 0) {
      int r = j & 31; int t = j >> 5;
      int g = t % 33; t /= 33;
      i = t * 1089 + g * 33 + r; stride = 1;
      w = (r == 0 || r == 31) ? 2.f : 1.f;
    } else if (dir == 1) {
      int r = j % 33; int t = j / 33; int g = t & 31; t >>= 5;
      i = t * 1089 + g * 33 + r; stride = 33;
      w = (g == 0 || g == 31) ? 2.f : 1.f;
    } else {
      int r = j % 33; int t = j / 33; int g = t % 33; t /= 33;
      int bb = t & 31; t >>= 5;
      i = (t * 33 + bb) * 1089 + g * 33 + r; stride = 1089;
      w = (bb == 0 || bb == 31) ? 2.f : 1.f;
    }
    float d = f[i] - f[i + stride];
    tv = fmaf(d * d, w, tv);
    mn += fmaxf(d, 0.f);
  }
  __shared__ float r1[256], r2[256];
  r1[threadIdx.x] = tv; r2[threadIdx.x] = mn; __syncthreads();
  for (int st = 128; st > 0; st >>= 1) {
    if (threadIdx.x < st) { r1[threadIdx.x] += r1[threadIdx.x + st];
                            r2[threadIdx.x] += r2[threadIdx.x + st]; }
    __syncthreads();
  }
  if (threadIdx.x == 0) {
    atomicAdd(&g_state[GS_ACCS], r1[0]);
    atomicAdd(&g_state[GS_ACCS + 1], r2[0]);
  }
}

// ---------- trilinear apply + blend + clip; finalize tv/mn ----------
__global__ __launch_bounds__(256) void kapply(
    const float* __restrict__ x, const float* __restrict__ F,
    const u16* __restrict__ Fa, float* __restrict__ out)
{
  int p = blockIdx.x * 256 + threadIdx.x;
  if (p == 0) {
    out[OUT_TV] = g_state[GS_ACCS] * (1.f / 418176.f);
    out[OUT_MN] = g_state[GS_ACCS + 1] * (1.f / 418176.f);
  }
  int b = p >> 20, yx = p & 1048575;
  size_t base = (size_t)b * 3145728u + yx;
  float xr = x[base];
  float xg = x[base + 1048576];
  float xb = x[base + 2097152];
  float a = g_state[GS_BLEND + b];
  float sr = fminf(fmaxf(xr, 0.f), 1.f) * 32.f;
  float sg = fminf(fmaxf(xg, 0.f), 1.f) * 32.f;
  float sb = fminf(fmaxf(xb, 0.f), 1.f) * 32.f;
  int ir = min((int)sr, 31), ig = min((int)sg, 31), ib = min((int)sb, 31);
  float fr = sr - ir, fg = sg - ig, fb = sb - ib;

  if (Fa) {
    const int cb = b * 35937 + ib * 1089 + ig * 33 + ir;
    const u32* Fu = (const u32*)Fa;
    u32 q[4][4];
    #pragma unroll
    for (int db = 0; db < 2; db++)
      #pragma unroll
      for (int dg = 0; dg < 2; dg++) {
        const u32* c0 = Fu + (size_t)(cb + db * 1089 + dg * 33) * 2;
        q[db * 2 + dg][0] = c0[0]; q[db * 2 + dg][1] = c0[1];
        q[db * 2 + dg][2] = c0[2]; q[db * 2 + dg][3] = c0[3];
      }
    #pragma unroll
    for (int c = 0; c < 3; c++) {
      const int k = c >> 1, sh = (c & 1) * 16;
      float v000 = h2f((u16)(q[0][k]     >> sh));
      float v001 = h2f((u16)(q[0][2 + k] >> sh));
      float v010 = h2f((u16)(q[1][k]     >> sh));
      float v011 = h2f((u16)(q[1][2 + k] >> sh));
      float v100 = h2f((u16)(q[2][k]     >> sh));
      float v101 = h2f((u16)(q[2][2 + k] >> sh));
      float v110 = h2f((u16)(q[3][k]     >> sh));
      float v111 = h2f((u16)(q[3][2 + k] >> sh));
      float c00 = v000 + fr * (v001 - v000);
      float c01 = v010 + fr * (v011 - v010);
      float c10 = v100 + fr * (v101 - v100);
      float c11 = v110 + fr * (v111 - v110);
      float c0 = c00 + fg * (c01 - c00);
      float c1 = c10 + fg * (c11 - c10);
      float v  = c0 + fb * (c1 - c0);
      float xv = (c == 0) ? xr : (c == 1) ? xg : xb;
      float o = fminf(fmaxf((1.f - a) * xv + a * v, 0.f), 1.f);
      out[(size_t)(b * 3 + c) * 1048576u + yx] = o;
    }
  } else {
    const float* Fb = F + (size_t)b * 107811u + ib * 1089 + ig * 33 + ir;
    #pragma unroll
    for (int c = 0; c < 3; c++) {
      const float* Fc = Fb + c * 35937;
      float v000 = Fc[0],    v001 = Fc[1];
      float v010 = Fc[33],   v011 = Fc[34];
      float v100 = Fc[1089], v101 = Fc[1090];
      float v110 = Fc[1122], v111 = Fc[1123];
      float c00 = v000 + fr * (v001 - v000);
      float c01 = v010 + fr * (v011 - v010);
      float c10 = v100 + fr * (v101 - v100);
      float c11 = v110 + fr * (v111 - v110);
      float c0 = c00 + fg * (c01 - c00);
      float c1 = c10 + fg * (c11 - c10);
      float v  = c0 + fb * (c1 - c0);
      float xv = (c == 0) ? xr : (c == 1) ? xg : xb;
      float o = fminf(fmaxf((1.f - a) * xv + a * v, 0.f), 1.f);
      out[(size_t)(b * 3 + c) * 1048576u + yx] = o;
    }
  }
}

extern "C" void kernel_launch(void* const* d_in, const int* in_sizes, int n_in,
                              void* d_out, int out_size, void* d_ws, size_t ws_size,
                              hipStream_t stream)
{
  (void)in_sizes; (void)n_in; (void)out_size;
  const float* x    = (const float*)d_in[0];
  const float* luts = (const float*)d_in[1];
  const float* wn_b1 = (const float*)d_in[3];
  const float* wn_b2 = (const float*)d_in[5];
  const float* wn_b3 = (const float*)d_in[7];
  const float* wn_b4 = (const float*)d_in[9];
  const float* wn_fw1 = (const float*)d_in[10], *wn_fb1 = (const float*)d_in[11];
  const float* wn_fw2 = (const float*)d_in[12], *wn_fb2 = (const float*)d_in[13];
  const float* bl_b1 = (const float*)d_in[15];
  const float* bl_b2 = (const float*)d_in[17];
  const float* bl_b3 = (const float*)d_in[19];
  const float* bl_b4 = (const float*)d_in[21];
  const float* bl_fw1 = (const float*)d_in[22], *bl_fb1 = (const float*)d_in[23];
  const float* bl_fw2 = (const float*)d_in[24], *bl_fb2 = (const float*)d_in[25];
  float* out = (float*)d_out;

  u16 *scrA, *scrB, *Fa;
  if (ws_size >= 50331648u) {
    scrA = (u16*)d_ws;
    scrB = (u16*)d_ws + 16777216;
    Fa = (u16*)d_ws;
  } else {
    scrA = (u16*)out;
    scrB = (u16*)out + 16777216;
    Fa = nullptr;                 // SoA fallback path in kapply
  }

  P2Args p2;
  const float* wsrc[8] = {(const float*)d_in[4],  (const float*)d_in[16],
                          (const float*)d_in[6],  (const float*)d_in[8],
                          (const float*)d_in[18], (const float*)d_in[20],
                          (const float*)d_in[2],  (const float*)d_in[14]};
  const int pI[8]   = {32, 16, 32, 64, 16, 32, 3, 3};
  const int pNTF[8] = {2, 1, 4, 4, 2, 2, 2, 1};
  const int pB[8]   = {WF_WN2, WF_BL2, WF_WN3, WF_WN4, WF_BL3, WF_BL4,
                       WF_WN1, WF_BL1};
  for (int l = 0; l < 8; l++) { p2.w[l] = wsrc[l]; p2.I[l] = pI[l];
                                p2.ntf[l] = pNTF[l]; p2.base[l] = pB[l]; }
  kprep2<<<dim3(348), 256, 0, stream>>>(p2);

  // ---- weight-net (WN), 2 batches per pass ----
  for (int b0 = 0; b0 < 4; b0 += 2) {
    const float* xb = x + (size_t)b0 * 3145728u;
    k12m<32,32,2,4><<<dim3(32,32,2), 256, 0, stream>>>(xb, WF_WN1, wn_b1, wn_b2, WF_WN2, scrA);
    k34m<32,64,2,4,1,false><<<dim3(16,16,4), 256, 0, stream>>>(scrA, wn_b3, WF_WN3, scrB, 512);
    k34m<64,64,2,4,2,true ><<<dim3(8,8,4),   256, 0, stream>>>(scrB, wn_b4, WF_WN4, scrA, 256);
    kmean<<<dim3(64,2), 256, 0, stream>>>(scrA, 64, GS_FEATWN + b0 * 64);
  }
  khead<64,8,false><<<1,256,0,stream>>>(wn_fw1, wn_fb1, wn_fw2, wn_fb2,
                                        GS_FEATWN, GS_W3D, out + OUT_W3D);

  // ---- blend-net (BL), 2 batches per pass ----
  for (int b0 = 0; b0 < 4; b0 += 2) {
    const float* xb = x + (size_t)b0 * 3145728u;
    k12m<16,16,1,2><<<dim3(32,32,2), 256, 0, stream>>>(xb, WF_BL1, bl_b1, bl_b2, WF_BL2, scrA);
    k34m<16,32,2,2,1,false><<<dim3(16,16,2), 256, 0, stream>>>(scrA, bl_b3, WF_BL3, scrB, 512);
    k34m<32,32,2,4,1,true ><<<dim3(8,8,2),   256, 0, stream>>>(scrB, bl_b4, WF_BL4, scrA, 256);
    kmean<<<dim3(32,2), 256, 0, stream>>>(scrA, 32, GS_FEATBL + b0 * 32);
  }
  khead<32,1,true ><<<1,256,0,stream>>>(bl_fw1, bl_fb1, bl_fw2, bl_fb2,
                                        GS_FEATBL, GS_BLEND, (float*)nullptr);

  // ---- LUT fuse (+fp16 AoS), TV, final apply ----
  kfuse<<<1685, 256, 0, stream>>>(luts, out + OUT_FUSED, Fa);
  ktv<<<512, 256, 0, stream>>>(out + OUT_FUSED);
  kapply<<<16384, 256, 0, stream>>>(x, out + OUT_FUSED, Fa, out);
}

// Round 4
// 500.477 us; speedup vs baseline: 3.5540x; 1.2887x over previous
//
#include <hip/hip_runtime.h>

typedef unsigned short u16;
typedef unsigned int u32;
typedef __attribute__((ext_vector_type(8))) short vbf8;   // 8 bf16 = 4 VGPR
typedef __attribute__((ext_vector_type(4))) short vs4;    // 4 bf16 = 8 B
typedef __attribute__((ext_vector_type(4))) float vf4;    // MFMA acc

// ---------- bf16 <-> f32 (bitwise; RNE on pack) ----------
__device__ __forceinline__ float b2f(u16 u) {
  union { unsigned int i; float f; } v; v.i = ((unsigned int)u) << 16; return v.f;
}
__device__ __forceinline__ u16 f2b(float f) {
  union { float f; unsigned int i; } v; v.f = f;
  unsigned int r = v.i + 0x7fffu + ((v.i >> 16) & 1u);
  return (u16)(r >> 16);
}
__device__ __forceinline__ u16 f2h(float f) {
  union { _Float16 h; u16 s; } cv; cv.h = (_Float16)f; return cv.s;
}
__device__ __forceinline__ float h2f(u16 u) {
  union { _Float16 h; u16 s; } cv; cv.s = u; return (float)cv.h;
}

// ---------- tiny cross-kernel state ------
__device__ float g_state[512];
#define GS_FEATWN 0      // 256
#define GS_FEATBL 256    // 128
#define GS_W3D    384    // 32
#define GS_BLEND  416    // 4
#define GS_ACCS   420    // 2

// ---------- MFMA-fragment-ordered bf16 conv weights ----------
// conv2..4 frag (kc,t,nt): 64 lanes x 8 bf16;
//   elem (l,j) = W[oc=nt*16+(l&15)][ic=kc*32+(l>>4)*8+j][t]; idx = (kc*9+t)*NTF+nt
// conv1 frag (mt): elem (l,j) = W[oc=mt*16+(l&15)][k=(l>>4)*8+j], k=ic*9+t, k>=27 pad0
__device__ __align__(16) u16 g_wfrag[89088];
#define WF_WN2 0       // NTF=2 KC=1 : 18 frags
#define WF_BL2 9216    // NTF=1 KC=1 :  9
#define WF_WN3 13824   // NTF=4 KC=1 : 36
#define WF_WN4 32256   // NTF=4 KC=2 : 72
#define WF_BL3 69120   // NTF=2 KC=1 : 18 (I=16 zero-pad)
#define WF_BL4 78336   // NTF=2 KC=1 : 18
#define WF_WN1 87552   // conv1: 2 frags
#define WF_BL1 88576   // conv1: 1 frag

// ---------- output layout (fp32 elements) ----------
#define OUT_FUSED 12582912
#define OUT_TV    13014156
#define OUT_MN    13014157
#define OUT_W3D   13014158

// ---------- prep: pack all conv weights into MFMA fragment order ----------
// Also zeroes the g_state feature accumulators (conv4 reduces via atomicAdd).
struct P2Args { const float* w[8]; int I[8]; int ntf[8]; int base[8]; };

__global__ __launch_bounds__(256) void kprep2(P2Args a) {
  if (blockIdx.x == 0 && threadIdx.x < 256) {
    g_state[threadIdx.x] = 0.f;
    if (threadIdx.x < 128) g_state[256 + threadIdx.x] = 0.f;
  }
  int i = blockIdx.x * 256 + threadIdx.x;   // grid 348*256 = 89088 exact
  int l = 0;
  #pragma unroll
  for (int k = 1; k < 8; k++) if (i >= a.base[k]) l = k;
  int e2 = i - a.base[l];
  int frag = e2 >> 9, e = e2 & 511;
  int ll = e >> 3, j = e & 7;
  if (l < 6) {
    int NTF = a.ntf[l];
    int kc = frag / (9 * NTF);
    int r = frag - kc * 9 * NTF;
    int t = r / NTF, nt = r - t * NTF;
    int I = a.I[l];
    int oc = nt * 16 + (ll & 15);
    int ic = kc * 32 + (ll >> 4) * 8 + j;
    g_wfrag[i] = (ic < I) ? f2b(a.w[l][(oc * I + ic) * 9 + t]) : (u16)0;
  } else {
    int k = (ll >> 4) * 8 + j;                  // k = ic*9 + tap
    int oc = frag * 16 + (ll & 15);
    g_wfrag[i] = (k < 27) ? f2b(a.w[l][oc * 27 + k]) : (u16)0;
  }
}

// ---------- fused conv1(stride1)+conv2(stride2), both relu, pad1 ----------
// 512 threads / 8 waves per block (same LDS as 256-thr version -> 2 blk/CU,
// 16 waves/CU for latency hiding).
// conv1: K=27(->32) GEMM on MFMA, A=weights (rows=oc), B=x-patches (cols=pixels).
// conv2: 9 tap-GEMMs on MFMA. Output NHWC [z][512][512][C2].
template<int C1, int C2, int NT, int NG>
__global__ __launch_bounds__(512) void k12m(
    const float* __restrict__ x, int wf1o, const float* __restrict__ b1,
    const float* __restrict__ b2, int wfo, u16* __restrict__ h2)
{
  constexpr int FS = (NG == 4) ? 1 : 2;
  constexpr int MT1 = C1 / 16;
  __shared__ __align__(16) u16 xs[3][35][36];
  __shared__ __align__(16) u16 h1p[2][33][17][C1];
  __shared__ __align__(16) u16 zbuf[8];
  const int tid = threadIdx.x;
  const int lane = tid & 63, wv = tid >> 6;       // wv 0..7
  const int ocl = lane & 15;   // D col index (pixel in conv1, oc in conv2)
  const int kg  = lane >> 4;   // K-group
  const int oy0 = blockIdx.y * 16, ox0 = blockIdx.x * 16;
  const int hy0 = 2 * oy0 - 1, hx0 = 2 * ox0 - 1;
  const float* xb = x + (size_t)blockIdx.z * 3145728u;
  u16* h2b = h2 + (size_t)blockIdx.z * 262144u * (size_t)C2;

  if (tid < 8) zbuf[tid] = 0;
  for (int i = tid; i < 3675; i += 512) {
    int ic = i / 1225, rem = i - ic * 1225;
    int yy = rem / 35, xx = rem - yy * 35;
    int gy = hy0 - 1 + yy, gx = hx0 - 1 + xx;
    float v = 0.f;
    if ((unsigned)gy < 1024u && (unsigned)gx < 1024u)
      v = xb[ic * 1048576 + (gy << 10) + gx];
    xs[ic][yy][xx] = f2b(v);
  }

  // conv1 weight frags + biases (registers, uniform per lane)
  vbf8 wa1[MT1];
  float bias1[MT1][4];
  {
    const u16* wfb = g_wfrag + wf1o + lane * 8;
    #pragma unroll
    for (int mt = 0; mt < MT1; mt++) {
      wa1[mt] = *(const vbf8*)(wfb + mt * 512);
      #pragma unroll
      for (int j = 0; j < 4; j++)
        bias1[mt][j] = b1[mt * 16 + kg * 4 + j];
    }
  }
  __syncthreads();

  // ---- conv1: 69 pixel-tiles of 16 over the 33x33 halo ----
  for (int pt = wv; pt < 69; pt += 8) {
    const int p = pt * 16 + ocl;
    const bool ok = (p < 1089);
    const int pc = ok ? p : 1088;
    const int py = pc / 33, px = pc - py * 33;
    vbf8 bfrag;
    #pragma unroll
    for (int j = 0; j < 8; j++) {
      const int k = kg * 8 + j;
      u16 v = 0;
      if (k < 27) {
        const int ic = k / 9, tt = k - ic * 9;
        v = xs[ic][py + tt / 3][px + tt % 3];
      }
      bfrag[j] = (short)v;
    }
    const int par = px & 1, hx = px >> 1;
    const int f = (hx >> FS) & (NG - 1);
    #pragma unroll
    for (int mt = 0; mt < MT1; mt++) {
      vf4 z = {0.f, 0.f, 0.f, 0.f};
      vf4 d = __builtin_amdgcn_mfma_f32_16x16x32_bf16(wa1[mt], bfrag, z, 0, 0, 0);
      if (ok) {
        vs4 pk;
        #pragma unroll
        for (int j = 0; j < 4; j++)
          pk[j] = (short)f2b(fmaxf(d[j] + bias1[mt][j], 0.f));
        const int q = kg + 4 * mt;        // oc-quad index
        *(vs4*)(&h1p[par][py][hx][((q >> 1) ^ f) * 8 + (q & 1) * 4]) = pk;
      }
    }
  }
  __syncthreads();

  // ---- conv2: tap-decomposed GEMM; each wave owns 2 output rows ----
  vbf8 bw[9 * NT];
  {
    const u16* wfb = g_wfrag + wfo + lane * 8;
    #pragma unroll
    for (int i = 0; i < 9 * NT; i++)
      bw[i] = *(const vbf8*)(wfb + i * 512);
  }

  vf4 acc2[2][NT];
  #pragma unroll
  for (int nt = 0; nt < NT; nt++) {
    float bv = b2[nt * 16 + ocl];
    #pragma unroll
    for (int mt = 0; mt < 2; mt++) {
      vf4 c; c[0] = bv; c[1] = bv; c[2] = bv; c[3] = bv;
      acc2[mt][nt] = c;
    }
  }

  #pragma unroll
  for (int t = 0; t < 9; t++) {
    const int ty = t / 3, tx = t % 3;
    const int par = tx & 1;
    const int hx = (lane & 15) + (tx >> 1);
    const int f = (hx >> FS) & (NG - 1);
    #pragma unroll
    for (int mt = 0; mt < 2; mt++) {
      const int y = 2 * (wv * 2 + mt) + ty;
      const u16* ap;
      if constexpr (NG == 4) {
        ap = &h1p[par][y][hx][((kg ^ f) & 3) * 8];
      } else {
        ap = (kg < NG) ? &h1p[par][y][hx][((kg ^ f) & (NG - 1)) * 8] : zbuf;
      }
      vbf8 a = *(const vbf8*)ap;
      #pragma unroll
      for (int nt = 0; nt < NT; nt++)
        acc2[mt][nt] = __builtin_amdgcn_mfma_f32_16x16x32_bf16(
            a, bw[t * NT + nt], acc2[mt][nt], 0, 0, 0);
    }
  }

  // ---- epilogue: NHWC [z][512][512][C2] ----
  #pragma unroll
  for (int mt = 0; mt < 2; mt++) {
    const int oy = oy0 + wv * 2 + mt;
    #pragma unroll
    for (int nt = 0; nt < NT; nt++) {
      #pragma unroll
      for (int j = 0; j < 4; j++) {
        const int ox = ox0 + kg * 4 + j;
        h2b[((size_t)(oy << 9) + ox) * C2 + nt * 16 + ocl] =
            f2b(fmaxf(acc2[mt][nt][j], 0.f));
      }
    }
  }
}

// ---------- stride-2 conv on MFMA (conv3/conv4), NHWC in, 512 threads ----------
// grid (HO/16, HO/16, 2*OCG). If REDUCE: no store; block-reduce relu(acc) over
// pixels and atomicAdd channel means into g_state[gofs + zb2*COUT + oc].
template<int CIN, int COUT, int NT, int NG, int KC, bool REDUCE>
__global__ __launch_bounds__(512) void k34m(
    const u16* __restrict__ in, const float* __restrict__ bia,
    int wfo, u16* __restrict__ out, int HIN, int gofs)
{
  constexpr int FS = (NG == 4) ? 1 : 2;
  constexpr int NTF = COUT / 16;
  constexpr int OCG = COUT / (NT * 16);
  __shared__ __align__(16) u16 h1p[2][33][17][NG * 8];
  __shared__ __align__(16) u16 zbuf[8];
  __shared__ float rsum[NT * 16];
  const int HO = HIN >> 1;
  const int tid = threadIdx.x;
  const int lane = tid & 63, wv = tid >> 6;
  const int zb2 = blockIdx.z / OCG;
  const int og = blockIdx.z - zb2 * OCG;
  const int oy0 = blockIdx.y * 16, ox0 = blockIdx.x * 16;
  const int iy0 = 2 * oy0 - 1, ix0 = 2 * ox0 - 1;
  const u16* inb = in + (size_t)zb2 * (size_t)HIN * HIN * CIN;

  if (tid < 8) zbuf[tid] = 0;
  if (REDUCE && tid < NT * 16) rsum[tid] = 0.f;

  const int ocl = lane & 15;
  const int kg  = lane >> 4;

  vf4 acc2[2][NT];
  #pragma unroll
  for (int nt = 0; nt < NT; nt++) {
    float bv = bia[og * NT * 16 + nt * 16 + ocl];
    #pragma unroll
    for (int mt = 0; mt < 2; mt++) {
      vf4 c; c[0] = bv; c[1] = bv; c[2] = bv; c[3] = bv;
      acc2[mt][nt] = c;
    }
  }

  vbf8 bw[9 * NT];

  for (int kc = 0; kc < KC; kc++) {
    if (kc) __syncthreads();
    // stage input chunk (32 ic) into swizzled parity-split LDS
    for (int i = tid; i < 33 * 33 * NG; i += 512) {
      int g = i & (NG - 1);
      int pp = i / NG;
      int yy = pp / 33, xx = pp - yy * 33;
      int gy = iy0 + yy, gx = ix0 + xx;
      vbf8 v = {0, 0, 0, 0, 0, 0, 0, 0};
      if ((unsigned)gy < (unsigned)HIN && (unsigned)gx < (unsigned)HIN)
        v = *(const vbf8*)(inb + (size_t)(gy * HIN + gx) * CIN + kc * 32 + g * 8);
      const int par = xx & 1, hx = xx >> 1;
      const int f = (hx >> FS) & (NG - 1);
      *(vbf8*)(&h1p[par][yy][hx][(g ^ f) * 8]) = v;
    }
    // chunk weights
    {
      const u16* wfb = g_wfrag + wfo + lane * 8;
      #pragma unroll
      for (int t = 0; t < 9; t++)
        #pragma unroll
        for (int nt = 0; nt < NT; nt++)
          bw[t * NT + nt] =
              *(const vbf8*)(wfb + (size_t)((kc * 9 + t) * NTF + og * NT + nt) * 512);
    }
    __syncthreads();

    #pragma unroll
    for (int t = 0; t < 9; t++) {
      const int ty = t / 3, tx = t % 3;
      const int par = tx & 1;
      const int hx = (lane & 15) + (tx >> 1);
      const int f = (hx >> FS) & (NG - 1);
      #pragma unroll
      for (int mt = 0; mt < 2; mt++) {
        const int y = 2 * (wv * 2 + mt) + ty;
        const u16* ap;
        if constexpr (NG == 4) {
          ap = &h1p[par][y][hx][((kg ^ f) & 3) * 8];
        } else {
          ap = (kg < NG) ? &h1p[par][y][hx][((kg ^ f) & (NG - 1)) * 8] : zbuf;
        }
        vbf8 a = *(const vbf8*)ap;
        #pragma unroll
        for (int nt = 0; nt < NT; nt++)
          acc2[mt][nt] = __builtin_amdgcn_mfma_f32_16x16x32_bf16(
              a, bw[t * NT + nt], acc2[mt][nt], 0, 0, 0);
      }
    }
  }

  if constexpr (REDUCE) {
    #pragma unroll
    for (int nt = 0; nt < NT; nt++) {
      float part = 0.f;
      #pragma unroll
      for (int mt = 0; mt < 2; mt++)
        #pragma unroll
        for (int j = 0; j < 4; j++)
          part += fmaxf(acc2[mt][nt][j], 0.f);
      atomicAdd(&rsum[nt * 16 + ocl], part);
    }
    __syncthreads();
    if (tid < NT * 16)
      atomicAdd(&g_state[gofs + zb2 * COUT + og * NT * 16 + tid],
                rsum[tid] * (1.f / 16384.f));
  } else {
    #pragma unroll
    for (int mt = 0; mt < 2; mt++) {
      const int oy = oy0 + wv * 2 + mt;
      #pragma unroll
      for (int nt = 0; nt < NT; nt++) {
        const int oc = og * NT * 16 + nt * 16 + ocl;
        #pragma unroll
        for (int j = 0; j < 4; j++) {
          const int ox = ox0 + kg * 4 + j;
          out[((size_t)zb2 * HO * HO + (size_t)(oy * HO + ox)) * COUT + oc] =
              f2b(fmaxf(acc2[mt][nt][j], 0.f));
        }
      }
    }
  }
}

// ---------- FC head ----------
template<int CF, int NOUT, bool SIG>
__global__ __launch_bounds__(256) void khead(
    const float* __restrict__ fw1, const float* __restrict__ fb1,
    const float* __restrict__ fw2, const float* __restrict__ fb2,
    int feato, int outo, float* out_f)
{
  __shared__ float fc1[4 * CF];
  const int tid = threadIdx.x;
  if (tid < 4 * CF) {
    int b = tid / CF, o = tid - b * CF;
    float s = fb1[o];
    for (int i = 0; i < CF; i++)
      s = fmaf(g_state[feato + b * CF + i], fw1[o * CF + i], s);
    fc1[tid] = fmaxf(s, 0.f);
  }
  __syncthreads();
  if (tid < 4 * NOUT) {
    int b = tid / NOUT, n = tid - b * NOUT;
    float s = fb2[n];
    for (int i = 0; i < CF; i++)
      s = fmaf(fc1[b * CF + i], fw2[n * CF + i], s);
    if (SIG) s = 1.f / (1.f + expf(-s));
    g_state[outo + b * NOUT + n] = s;
    if (out_f) out_f[b * NOUT + n] = s;
  }
}

// ---------- fused LUT = clip(w3d @ luts + identity, 0,1); also fp16 AoS copy ----------
__global__ __launch_bounds__(256) void kfuse(
    const float* __restrict__ luts, float* __restrict__ outF,
    u16* __restrict__ Fa)
{
  if (blockIdx.x == 0 && threadIdx.x == 0) {
    g_state[GS_ACCS] = 0.f; g_state[GS_ACCS + 1] = 0.f;
  }
  int idx = blockIdx.x * 256 + threadIdx.x;
  if (idx >= 431244) return;
  int n = idx / 107811, m = idx - n * 107811;
  int c = m / 35937, q = m - c * 35937;
  int bq = q / 1089, r2 = q - bq * 1089;
  int gq = r2 / 33, rq = r2 - gq * 33;
  int id = (c == 0) ? rq : (c == 1) ? gq : bq;
  float s = (float)id * (1.f / 32.f);
  #pragma unroll
  for (int k = 0; k < 8; k++)
    s = fmaf(g_state[GS_W3D + n * 8 + k], luts[k * 107811 + m], s);
  s = fminf(fmaxf(s, 0.f), 1.f);
  outF[idx] = s;
  if (Fa) Fa[(n * 35937 + q) * 4 + c] = f2h(s);
}

// ---------- TV + monotonicity reductions over fused ----------
__global__ __launch_bounds__(256) void ktv(const float* __restrict__ f) {
  const int Nr = 418176;
  float tv = 0.f, mn = 0.f;
  for (int e = blockIdx.x * 256 + threadIdx.x; e < 3 * Nr; e += gridDim.x * 256) {
    int dir = e / Nr, j = e - dir * Nr;
    int i, stride; float w;
    if (dir == 0) {
      int r = j & 31; int t = j >> 5;
      int g = t % 33; t /= 33;
      i = t * 1089 + g * 33 + r; stride = 1;
      w = (r == 0 || r == 31) ? 2.f : 1.f;
    } else if (dir == 1) {
      int r = j % 33; int t = j / 33; int g = t & 31; t >>= 5;
      i = t * 1089 + g * 33 + r; stride = 33;
      w = (g == 0 || g == 31) ? 2.f : 1.f;
    } else {
      int r = j % 33; int t = j / 33; int g = t % 33; t /= 33;
      int bb = t & 31; t >>= 5;
      i = (t * 33 + bb) * 1089 + g * 33 + r; stride = 1089;
      w = (bb == 0 || bb == 31) ? 2.f : 1.f;
    }
    float d = f[i] - f[i + stride];
    tv = fmaf(d * d, w, tv);
    mn += fmaxf(d, 0.f);
  }
  __shared__ float r1[256], r2[256];
  r1[threadIdx.x] = tv; r2[threadIdx.x] = mn; __syncthreads();
  for (int st = 128; st > 0; st >>= 1) {
    if (threadIdx.x < st) { r1[threadIdx.x] += r1[threadIdx.x + st];
                            r2[threadIdx.x] += r2[threadIdx.x + st]; }
    __syncthreads();
  }
  if (threadIdx.x == 0) {
    atomicAdd(&g_state[GS_ACCS], r1[0]);
    atomicAdd(&g_state[GS_ACCS + 1], r2[0]);
  }
}

// ---------- trilinear apply + blend + clip; finalize tv/mn ----------
__global__ __launch_bounds__(256) void kapply(
    const float* __restrict__ x, const float* __restrict__ F,
    const u16* __restrict__ Fa, float* __restrict__ out)
{
  int p = blockIdx.x * 256 + threadIdx.x;
  if (p == 0) {
    out[OUT_TV] = g_state[GS_ACCS] * (1.f / 418176.f);
    out[OUT_MN] = g_state[GS_ACCS + 1] * (1.f / 418176.f);
  }
  int b = p >> 20, yx = p & 1048575;
  size_t base = (size_t)b * 3145728u + yx;
  float xr = x[base];
  float xg = x[base + 1048576];
  float xb = x[base + 2097152];
  float a = g_state[GS_BLEND + b];
  float sr = fminf(fmaxf(xr, 0.f), 1.f) * 32.f;
  float sg = fminf(fmaxf(xg, 0.f), 1.f) * 32.f;
  float sb = fminf(fmaxf(xb, 0.f), 1.f) * 32.f;
  int ir = min((int)sr, 31), ig = min((int)sg, 31), ib = min((int)sb, 31);
  float fr = sr - ir, fg = sg - ig, fb = sb - ib;

  if (Fa) {
    const int cb = b * 35937 + ib * 1089 + ig * 33 + ir;
    const u32* Fu = (const u32*)Fa;
    u32 q[4][4];
    #pragma unroll
    for (int db = 0; db < 2; db++)
      #pragma unroll
      for (int dg = 0; dg < 2; dg++) {
        const u32* c0 = Fu + (size_t)(cb + db * 1089 + dg * 33) * 2;
        q[db * 2 + dg][0] = c0[0]; q[db * 2 + dg][1] = c0[1];
        q[db * 2 + dg][2] = c0[2]; q[db * 2 + dg][3] = c0[3];
      }
    #pragma unroll
    for (int c = 0; c < 3; c++) {
      const int k = c >> 1, sh = (c & 1) * 16;
      float v000 = h2f((u16)(q[0][k]     >> sh));
      float v001 = h2f((u16)(q[0][2 + k] >> sh));
      float v010 = h2f((u16)(q[1][k]     >> sh));
      float v011 = h2f((u16)(q[1][2 + k] >> sh));
      float v100 = h2f((u16)(q[2][k]     >> sh));
      float v101 = h2f((u16)(q[2][2 + k] >> sh));
      float v110 = h2f((u16)(q[3][k]     >> sh));
      float v111 = h2f((u16)(q[3][2 + k] >> sh));
      float c00 = v000 + fr * (v001 - v000);
      float c01 = v010 + fr * (v011 - v010);
      float c10 = v100 + fr * (v101 - v100);
      float c11 = v110 + fr * (v111 - v110);
      float c0 = c00 + fg * (c01 - c00);
      float c1 = c10 + fg * (c11 - c10);
      float v  = c0 + fb * (c1 - c0);
      float xv = (c == 0) ? xr : (c == 1) ? xg : xb;
      float o = fminf(fmaxf((1.f - a) * xv + a * v, 0.f), 1.f);
      out[(size_t)(b * 3 + c) * 1048576u + yx] = o;
    }
  } else {
    const float* Fb = F + (size_t)b * 107811u + ib * 1089 + ig * 33 + ir;
    #pragma unroll
    for (int c = 0; c < 3; c++) {
      const float* Fc = Fb + c * 35937;
      float v000 = Fc[0],    v001 = Fc[1];
      float v010 = Fc[33],   v011 = Fc[34];
      float v100 = Fc[1089], v101 = Fc[1090];
      float v110 = Fc[1122], v111 = Fc[1123];
      float c00 = v000 + fr * (v001 - v000);
      float c01 = v010 + fr * (v011 - v010);
      float c10 = v100 + fr * (v101 - v100);
      float c11 = v110 + fr * (v111 - v110);
      float c0 = c00 + fg * (c01 - c00);
      float c1 = c10 + fg * (c11 - c10);
      float v  = c0 + fb * (c1 - c0);
      float xv = (c == 0) ? xr : (c == 1) ? xg : xb;
      float o = fminf(fmaxf((1.f - a) * xv + a * v, 0.f), 1.f);
      out[(size_t)(b * 3 + c) * 1048576u + yx] = o;
    }
  }
}

extern "C" void kernel_launch(void* const* d_in, const int* in_sizes, int n_in,
                              void* d_out, int out_size, void* d_ws, size_t ws_size,
                              hipStream_t stream)
{
  (void)in_sizes; (void)n_in; (void)out_size;
  const float* x    = (const float*)d_in[0];
  const float* luts = (const float*)d_in[1];
  const float* wn_b1 = (const float*)d_in[3];
  const float* wn_b2 = (const float*)d_in[5];
  const float* wn_b3 = (const float*)d_in[7];
  const float* wn_b4 = (const float*)d_in[9];
  const float* wn_fw1 = (const float*)d_in[10], *wn_fb1 = (const float*)d_in[11];
  const float* wn_fw2 = (const float*)d_in[12], *wn_fb2 = (const float*)d_in[13];
  const float* bl_b1 = (const float*)d_in[15];
  const float* bl_b2 = (const float*)d_in[17];
  const float* bl_b3 = (const float*)d_in[19];
  const float* bl_b4 = (const float*)d_in[21];
  const float* bl_fw1 = (const float*)d_in[22], *bl_fb1 = (const float*)d_in[23];
  const float* bl_fw2 = (const float*)d_in[24], *bl_fb2 = (const float*)d_in[25];
  float* out = (float*)d_out;

  u16 *scrA, *scrB, *Fa;
  if (ws_size >= 50331648u) {
    scrA = (u16*)d_ws;
    scrB = (u16*)d_ws + 16777216;
    Fa = (u16*)d_ws;
  } else {
    scrA = (u16*)out;
    scrB = (u16*)out + 16777216;
    Fa = nullptr;                 // SoA fallback path in kapply
  }

  P2Args p2;
  const float* wsrc[8] = {(const float*)d_in[4],  (const float*)d_in[16],
                          (const float*)d_in[6],  (const float*)d_in[8],
                          (const float*)d_in[18], (const float*)d_in[20],
                          (const float*)d_in[2],  (const float*)d_in[14]};
  const int pI[8]   = {32, 16, 32, 64, 16, 32, 3, 3};
  const int pNTF[8] = {2, 1, 4, 4, 2, 2, 2, 1};
  const int pB[8]   = {WF_WN2, WF_BL2, WF_WN3, WF_WN4, WF_BL3, WF_BL4,
                       WF_WN1, WF_BL1};
  for (int l = 0; l < 8; l++) { p2.w[l] = wsrc[l]; p2.I[l] = pI[l];
                                p2.ntf[l] = pNTF[l]; p2.base[l] = pB[l]; }
  kprep2<<<dim3(348), 256, 0, stream>>>(p2);

  // ---- weight-net (WN), 2 batches per pass ----
  for (int b0 = 0; b0 < 4; b0 += 2) {
    const float* xb = x + (size_t)b0 * 3145728u;
    k12m<32,32,2,4><<<dim3(32,32,2), 512, 0, stream>>>(xb, WF_WN1, wn_b1, wn_b2, WF_WN2, scrA);
    k34m<32,64,2,4,1,false><<<dim3(16,16,4), 512, 0, stream>>>(scrA, wn_b3, WF_WN3, scrB, 512, 0);
    k34m<64,64,2,4,2,true ><<<dim3(8,8,4),   512, 0, stream>>>(scrB, wn_b4, WF_WN4, scrA, 256, GS_FEATWN + b0 * 64);
  }
  khead<64,8,false><<<1,256,0,stream>>>(wn_fw1, wn_fb1, wn_fw2, wn_fb2,
                                        GS_FEATWN, GS_W3D, out + OUT_W3D);

  // ---- blend-net (BL), 2 batches per pass ----
  for (int b0 = 0; b0 < 4; b0 += 2) {
    const float* xb = x + (size_t)b0 * 3145728u;
    k12m<16,16,1,2><<<dim3(32,32,2), 512, 0, stream>>>(xb, WF_BL1, bl_b1, bl_b2, WF_BL2, scrA);
    k34m<16,32,2,2,1,false><<<dim3(16,16,2), 512, 0, stream>>>(scrA, bl_b3, WF_BL3, scrB, 512, 0);
    k34m<32,32,2,4,1,true ><<<dim3(8,8,2),   512, 0, stream>>>(scrB, bl_b4, WF_BL4, scrA, 256, GS_FEATBL + b0 * 32);
  }
  khead<32,1,true ><<<1,256,0,stream>>>(bl_fw1, bl_fb1, bl_fw2, bl_fb2,
                                        GS_FEATBL, GS_BLEND, (float*)nullptr);

  // ---- LUT fuse (+fp16 AoS), TV, final apply ----
  kfuse<<<1685, 256, 0, stream>>>(luts, out + OUT_FUSED, Fa);
  ktv<<<512, 256, 0, stream>>>(out + OUT_FUSED);
  kapply<<<16384, 256, 0, stream>>>(x, out + OUT_FUSED, Fa, out);
}

// Round 5
// 490.336 us; speedup vs baseline: 3.6275x; 1.0207x over previous
//
#include <hip/hip_runtime.h>

typedef unsigned short u16;
typedef unsigned int u32;
typedef __attribute__((ext_vector_type(8))) short vbf8;   // 8 bf16 = 4 VGPR
typedef __attribute__((ext_vector_type(4))) short vs4;    // 4 bf16 = 8 B
typedef __attribute__((ext_vector_type(4))) float vf4;    // MFMA acc / float4

// ---------- bf16 <-> f32 (bitwise; RNE on pack) ----------
__device__ __forceinline__ float b2f(u16 u) {
  union { unsigned int i; float f; } v; v.i = ((unsigned int)u) << 16; return v.f;
}
__device__ __forceinline__ u16 f2b(float f) {
  union { float f; unsigned int i; } v; v.f = f;
  unsigned int r = v.i + 0x7fffu + ((v.i >> 16) & 1u);
  return (u16)(r >> 16);
}
__device__ __forceinline__ u16 f2h(float f) {
  union { _Float16 h; u16 s; } cv; cv.h = (_Float16)f; return cv.s;
}
__device__ __forceinline__ float h2f(u16 u) {
  union { _Float16 h; u16 s; } cv; cv.s = u; return (float)cv.h;
}

// ---------- tiny cross-kernel state ------
__device__ float g_state[512];
#define GS_FEATWN 0      // 256
#define GS_FEATBL 256    // 128
#define GS_W3D    384    // 32
#define GS_BLEND  416    // 4
#define GS_ACCS   420    // 2

// ---------- MFMA-fragment-ordered bf16 conv weights ----------
// conv2..4 frag (kc,t,nt): 64 lanes x 8 bf16;
//   elem (l,j) = W[oc=nt*16+(l&15)][ic=kc*32+(l>>4)*8+j][t]; idx = (kc*9+t)*NTF+nt
// conv1 frag (mt): elem (l,j) = W[oc=mt*16+(l&15)][k=(l>>4)*8+j], k=ic*9+t, k>=27 pad0
__device__ __align__(16) u16 g_wfrag[89088];
#define WF_WN2 0       // NTF=2 KC=1 : 18 frags
#define WF_BL2 9216    // NTF=1 KC=1 :  9
#define WF_WN3 13824   // NTF=4 KC=1 : 36
#define WF_WN4 32256   // NTF=4 KC=2 : 72
#define WF_BL3 69120   // NTF=2 KC=1 : 18 (I=16 zero-pad)
#define WF_BL4 78336   // NTF=2 KC=1 : 18
#define WF_WN1 87552   // conv1: 2 frags
#define WF_BL1 88576   // conv1: 1 frag

// ---------- output layout (fp32 elements) ----------
#define OUT_FUSED 12582912
#define OUT_TV    13014156
#define OUT_MN    13014157
#define OUT_W3D   13014158

// ---------- prep: pack all conv weights into MFMA fragment order ----------
struct P2Args { const float* w[8]; int I[8]; int ntf[8]; int base[8]; };

__global__ __launch_bounds__(256) void kprep2(P2Args a) {
  if (blockIdx.x == 0 && threadIdx.x < 256) {
    g_state[threadIdx.x] = 0.f;
    if (threadIdx.x < 128) g_state[256 + threadIdx.x] = 0.f;
  }
  int i = blockIdx.x * 256 + threadIdx.x;   // grid 348*256 = 89088 exact
  int l = 0;
  #pragma unroll
  for (int k = 1; k < 8; k++) if (i >= a.base[k]) l = k;
  int e2 = i - a.base[l];
  int frag = e2 >> 9, e = e2 & 511;
  int ll = e >> 3, j = e & 7;
  if (l < 6) {
    int NTF = a.ntf[l];
    int kc = frag / (9 * NTF);
    int r = frag - kc * 9 * NTF;
    int t = r / NTF, nt = r - t * NTF;
    int I = a.I[l];
    int oc = nt * 16 + (ll & 15);
    int ic = kc * 32 + (ll >> 4) * 8 + j;
    g_wfrag[i] = (ic < I) ? f2b(a.w[l][(oc * I + ic) * 9 + t]) : (u16)0;
  } else {
    int k = (ll >> 4) * 8 + j;                  // k = ic*9 + tap
    int oc = frag * 16 + (ll & 15);
    g_wfrag[i] = (k < 27) ? f2b(a.w[l][oc * 27 + k]) : (u16)0;
  }
}

// ---------- merged WN+BL conv1+conv2 (ws path), 512 threads ----------
// Stages x once; WN conv1->conv2 then BL conv1->conv2 reusing the same LDS h1.
__global__ __launch_bounds__(512) void k12d(
    const float* __restrict__ x,
    const float* __restrict__ wb1, const float* __restrict__ wb2,
    const float* __restrict__ bb1, const float* __restrict__ bb2,
    u16* __restrict__ h2w, u16* __restrict__ h2b)
{
  __shared__ __align__(16) u16 xs[3][35][36];
  __shared__ __align__(16) u16 h1[35904];      // 2*33*17*32
  __shared__ __align__(16) u16 zbuf[8];
  const int tid = threadIdx.x;
  const int lane = tid & 63, wv = tid >> 6;
  const int ocl = lane & 15;
  const int kg  = lane >> 4;
  const int oy0 = blockIdx.y * 16, ox0 = blockIdx.x * 16;
  const int hy0 = 2 * oy0 - 1, hx0 = 2 * ox0 - 1;
  const float* xb = x + (size_t)blockIdx.z * 3145728u;
  u16* h2wb = h2w + (size_t)blockIdx.z * 262144u * 32u;
  u16* h2bb = h2b + (size_t)blockIdx.z * 262144u * 16u;

  if (tid < 8) zbuf[tid] = 0;
  for (int i = tid; i < 3675; i += 512) {
    int ic = i / 1225, rem = i - ic * 1225;
    int yy = rem / 35, xx = rem - yy * 35;
    int gy = hy0 - 1 + yy, gx = hx0 - 1 + xx;
    float v = 0.f;
    if ((unsigned)gy < 1024u && (unsigned)gx < 1024u)
      v = xb[ic * 1048576 + (gy << 10) + gx];
    xs[ic][yy][xx] = f2b(v);
  }

  // conv1 weight frags (WN: 2 tiles, BL: 1)
  vbf8 wa1[2], wa1b;
  float bias1[2][4], bias1b[4];
  {
    const u16* wfb = g_wfrag + lane * 8;
    wa1[0] = *(const vbf8*)(wfb + WF_WN1);
    wa1[1] = *(const vbf8*)(wfb + WF_WN1 + 512);
    wa1b   = *(const vbf8*)(wfb + WF_BL1);
    #pragma unroll
    for (int j = 0; j < 4; j++) {
      bias1[0][j] = wb1[kg * 4 + j];
      bias1[1][j] = wb1[16 + kg * 4 + j];
      bias1b[j]   = bb1[kg * 4 + j];
    }
  }
  __syncthreads();

  // ======== WN conv1 (C1=32, NG=4, FS=1) ========
  for (int pt = wv; pt < 69; pt += 8) {
    const int p = pt * 16 + ocl;
    const bool ok = (p < 1089);
    const int pc = ok ? p : 1088;
    const int py = pc / 33, px = pc - py * 33;
    vbf8 bfrag;
    #pragma unroll
    for (int j = 0; j < 8; j++) {
      const int k = kg * 8 + j;
      u16 v = 0;
      if (k < 27) {
        const int ic = k / 9, tt = k - ic * 9;
        v = xs[ic][py + tt / 3][px + tt % 3];
      }
      bfrag[j] = (short)v;
    }
    const int par = px & 1, hx = px >> 1;
    const int f = (hx >> 1) & 3;
    const int hb = ((par * 33 + py) * 17 + hx) * 32;
    #pragma unroll
    for (int mt = 0; mt < 2; mt++) {
      vf4 z = {0.f, 0.f, 0.f, 0.f};
      vf4 d = __builtin_amdgcn_mfma_f32_16x16x32_bf16(wa1[mt], bfrag, z, 0, 0, 0);
      if (ok) {
        vs4 pk;
        #pragma unroll
        for (int j = 0; j < 4; j++)
          pk[j] = (short)f2b(fmaxf(d[j] + bias1[mt][j], 0.f));
        const int q = kg + 4 * mt;
        *(vs4*)(&h1[hb + ((q >> 1) ^ f) * 8 + (q & 1) * 4]) = pk;
      }
    }
  }
  __syncthreads();

  // ======== WN conv2 (NT=2, NG=4) ========
  {
    vbf8 bw[18];
    const u16* wfb = g_wfrag + WF_WN2 + lane * 8;
    #pragma unroll
    for (int i = 0; i < 18; i++)
      bw[i] = *(const vbf8*)(wfb + i * 512);

    vf4 acc2[2][2];
    #pragma unroll
    for (int nt = 0; nt < 2; nt++) {
      float bv = wb2[nt * 16 + ocl];
      #pragma unroll
      for (int mt = 0; mt < 2; mt++) {
        vf4 c; c[0] = bv; c[1] = bv; c[2] = bv; c[3] = bv;
        acc2[mt][nt] = c;
      }
    }
    #pragma unroll
    for (int t = 0; t < 9; t++) {
      const int ty = t / 3, tx = t % 3;
      const int par = tx & 1;
      const int hx = (lane & 15) + (tx >> 1);
      const int f = (hx >> 1) & 3;
      #pragma unroll
      for (int mt = 0; mt < 2; mt++) {
        const int y = 2 * (wv * 2 + mt) + ty;
        vbf8 a = *(const vbf8*)(&h1[((par * 33 + y) * 17 + hx) * 32 + ((kg ^ f) & 3) * 8]);
        #pragma unroll
        for (int nt = 0; nt < 2; nt++)
          acc2[mt][nt] = __builtin_amdgcn_mfma_f32_16x16x32_bf16(
              a, bw[t * 2 + nt], acc2[mt][nt], 0, 0, 0);
      }
    }
    #pragma unroll
    for (int mt = 0; mt < 2; mt++) {
      const int oy = oy0 + wv * 2 + mt;
      #pragma unroll
      for (int nt = 0; nt < 2; nt++)
        #pragma unroll
        for (int j = 0; j < 4; j++) {
          const int ox = ox0 + kg * 4 + j;
          h2wb[((size_t)(oy << 9) + ox) * 32 + nt * 16 + ocl] =
              f2b(fmaxf(acc2[mt][nt][j], 0.f));
        }
    }
  }
  __syncthreads();

  // ======== BL conv1 (C1=16, NG=2, FS=2) ========
  for (int pt = wv; pt < 69; pt += 8) {
    const int p = pt * 16 + ocl;
    const bool ok = (p < 1089);
    const int pc = ok ? p : 1088;
    const int py = pc / 33, px = pc - py * 33;
    vbf8 bfrag;
    #pragma unroll
    for (int j = 0; j < 8; j++) {
      const int k = kg * 8 + j;
      u16 v = 0;
      if (k < 27) {
        const int ic = k / 9, tt = k - ic * 9;
        v = xs[ic][py + tt / 3][px + tt % 3];
      }
      bfrag[j] = (short)v;
    }
    const int par = px & 1, hx = px >> 1;
    const int f = (hx >> 2) & 1;
    vf4 z = {0.f, 0.f, 0.f, 0.f};
    vf4 d = __builtin_amdgcn_mfma_f32_16x16x32_bf16(wa1b, bfrag, z, 0, 0, 0);
    if (ok) {
      vs4 pk;
      #pragma unroll
      for (int j = 0; j < 4; j++)
        pk[j] = (short)f2b(fmaxf(d[j] + bias1b[j], 0.f));
      *(vs4*)(&h1[((par * 33 + py) * 17 + hx) * 16 + ((kg >> 1) ^ f) * 8 + (kg & 1) * 4]) = pk;
    }
  }
  __syncthreads();

  // ======== BL conv2 (NT=1, NG=2) ========
  {
    vbf8 bw[9];
    const u16* wfb = g_wfrag + WF_BL2 + lane * 8;
    #pragma unroll
    for (int i = 0; i < 9; i++)
      bw[i] = *(const vbf8*)(wfb + i * 512);

    vf4 acc2[2];
    {
      float bv = bb2[ocl];
      #pragma unroll
      for (int mt = 0; mt < 2; mt++) {
        vf4 c; c[0] = bv; c[1] = bv; c[2] = bv; c[3] = bv;
        acc2[mt] = c;
      }
    }
    #pragma unroll
    for (int t = 0; t < 9; t++) {
      const int ty = t / 3, tx = t % 3;
      const int par = tx & 1;
      const int hx = (lane & 15) + (tx >> 1);
      const int f = (hx >> 2) & 1;
      #pragma unroll
      for (int mt = 0; mt < 2; mt++) {
        const int y = 2 * (wv * 2 + mt) + ty;
        const u16* ap = (kg < 2)
            ? &h1[((par * 33 + y) * 17 + hx) * 16 + ((kg ^ f) & 1) * 8]
            : zbuf;
        vbf8 a = *(const vbf8*)ap;
        acc2[mt] = __builtin_amdgcn_mfma_f32_16x16x32_bf16(
            a, bw[t], acc2[mt], 0, 0, 0);
      }
    }
    #pragma unroll
    for (int mt = 0; mt < 2; mt++) {
      const int oy = oy0 + wv * 2 + mt;
      #pragma unroll
      for (int j = 0; j < 4; j++) {
        const int ox = ox0 + kg * 4 + j;
        h2bb[((size_t)(oy << 9) + ox) * 16 + ocl] =
            f2b(fmaxf(acc2[mt][j], 0.f));
      }
    }
  }
}

// ---------- separate conv1+conv2 (fallback path), 512 threads ----------
template<int C1, int C2, int NT, int NG>
__global__ __launch_bounds__(512) void k12m(
    const float* __restrict__ x, int wf1o, const float* __restrict__ b1,
    const float* __restrict__ b2, int wfo, u16* __restrict__ h2)
{
  constexpr int FS = (NG == 4) ? 1 : 2;
  constexpr int MT1 = C1 / 16;
  __shared__ __align__(16) u16 xs[3][35][36];
  __shared__ __align__(16) u16 h1p[2][33][17][C1];
  __shared__ __align__(16) u16 zbuf[8];
  const int tid = threadIdx.x;
  const int lane = tid & 63, wv = tid >> 6;
  const int ocl = lane & 15;
  const int kg  = lane >> 4;
  const int oy0 = blockIdx.y * 16, ox0 = blockIdx.x * 16;
  const int hy0 = 2 * oy0 - 1, hx0 = 2 * ox0 - 1;
  const float* xb = x + (size_t)blockIdx.z * 3145728u;
  u16* h2b = h2 + (size_t)blockIdx.z * 262144u * (size_t)C2;

  if (tid < 8) zbuf[tid] = 0;
  for (int i = tid; i < 3675; i += 512) {
    int ic = i / 1225, rem = i - ic * 1225;
    int yy = rem / 35, xx = rem - yy * 35;
    int gy = hy0 - 1 + yy, gx = hx0 - 1 + xx;
    float v = 0.f;
    if ((unsigned)gy < 1024u && (unsigned)gx < 1024u)
      v = xb[ic * 1048576 + (gy << 10) + gx];
    xs[ic][yy][xx] = f2b(v);
  }

  vbf8 wa1[MT1];
  float bias1[MT1][4];
  {
    const u16* wfb = g_wfrag + wf1o + lane * 8;
    #pragma unroll
    for (int mt = 0; mt < MT1; mt++) {
      wa1[mt] = *(const vbf8*)(wfb + mt * 512);
      #pragma unroll
      for (int j = 0; j < 4; j++)
        bias1[mt][j] = b1[mt * 16 + kg * 4 + j];
    }
  }
  __syncthreads();

  for (int pt = wv; pt < 69; pt += 8) {
    const int p = pt * 16 + ocl;
    const bool ok = (p < 1089);
    const int pc = ok ? p : 1088;
    const int py = pc / 33, px = pc - py * 33;
    vbf8 bfrag;
    #pragma unroll
    for (int j = 0; j < 8; j++) {
      const int k = kg * 8 + j;
      u16 v = 0;
      if (k < 27) {
        const int ic = k / 9, tt = k - ic * 9;
        v = xs[ic][py + tt / 3][px + tt % 3];
      }
      bfrag[j] = (short)v;
    }
    const int par = px & 1, hx = px >> 1;
    const int f = (hx >> FS) & (NG - 1);
    #pragma unroll
    for (int mt = 0; mt < MT1; mt++) {
      vf4 z = {0.f, 0.f, 0.f, 0.f};
      vf4 d = __builtin_amdgcn_mfma_f32_16x16x32_bf16(wa1[mt], bfrag, z, 0, 0, 0);
      if (ok) {
        vs4 pk;
        #pragma unroll
        for (int j = 0; j < 4; j++)
          pk[j] = (short)f2b(fmaxf(d[j] + bias1[mt][j], 0.f));
        const int q = kg + 4 * mt;
        *(vs4*)(&h1p[par][py][hx][((q >> 1) ^ f) * 8 + (q & 1) * 4]) = pk;
      }
    }
  }
  __syncthreads();

  vbf8 bw[9 * NT];
  {
    const u16* wfb = g_wfrag + wfo + lane * 8;
    #pragma unroll
    for (int i = 0; i < 9 * NT; i++)
      bw[i] = *(const vbf8*)(wfb + i * 512);
  }

  vf4 acc2[2][NT];
  #pragma unroll
  for (int nt = 0; nt < NT; nt++) {
    float bv = b2[nt * 16 + ocl];
    #pragma unroll
    for (int mt = 0; mt < 2; mt++) {
      vf4 c; c[0] = bv; c[1] = bv; c[2] = bv; c[3] = bv;
      acc2[mt][nt] = c;
    }
  }

  #pragma unroll
  for (int t = 0; t < 9; t++) {
    const int ty = t / 3, tx = t % 3;
    const int par = tx & 1;
    const int hx = (lane & 15) + (tx >> 1);
    const int f = (hx >> FS) & (NG - 1);
    #pragma unroll
    for (int mt = 0; mt < 2; mt++) {
      const int y = 2 * (wv * 2 + mt) + ty;
      const u16* ap;
      if constexpr (NG == 4) {
        ap = &h1p[par][y][hx][((kg ^ f) & 3) * 8];
      } else {
        ap = (kg < NG) ? &h1p[par][y][hx][((kg ^ f) & (NG - 1)) * 8] : zbuf;
      }
      vbf8 a = *(const vbf8*)ap;
      #pragma unroll
      for (int nt = 0; nt < NT; nt++)
        acc2[mt][nt] = __builtin_amdgcn_mfma_f32_16x16x32_bf16(
            a, bw[t * NT + nt], acc2[mt][nt], 0, 0, 0);
    }
  }

  #pragma unroll
  for (int mt = 0; mt < 2; mt++) {
    const int oy = oy0 + wv * 2 + mt;
    #pragma unroll
    for (int nt = 0; nt < NT; nt++) {
      #pragma unroll
      for (int j = 0; j < 4; j++) {
        const int ox = ox0 + kg * 4 + j;
        h2b[((size_t)(oy << 9) + ox) * C2 + nt * 16 + ocl] =
            f2b(fmaxf(acc2[mt][nt][j], 0.f));
      }
    }
  }
}

// ---------- stride-2 conv on MFMA (conv3/conv4), NHWC in, 512 threads ----------
template<int CIN, int COUT, int NT, int NG, int KC, bool REDUCE>
__global__ __launch_bounds__(512) void k34m(
    const u16* __restrict__ in, const float* __restrict__ bia,
    int wfo, u16* __restrict__ out, int HIN, int gofs)
{
  constexpr int FS = (NG == 4) ? 1 : 2;
  constexpr int NTF = COUT / 16;
  constexpr int OCG = COUT / (NT * 16);
  __shared__ __align__(16) u16 h1p[2][33][17][NG * 8];
  __shared__ __align__(16) u16 zbuf[8];
  __shared__ float rsum[NT * 16];
  const int HO = HIN >> 1;
  const int tid = threadIdx.x;
  const int lane = tid & 63, wv = tid >> 6;
  const int zb2 = blockIdx.z / OCG;
  const int og = blockIdx.z - zb2 * OCG;
  const int oy0 = blockIdx.y * 16, ox0 = blockIdx.x * 16;
  const int iy0 = 2 * oy0 - 1, ix0 = 2 * ox0 - 1;
  const u16* inb = in + (size_t)zb2 * (size_t)HIN * HIN * CIN;

  if (tid < 8) zbuf[tid] = 0;
  if (REDUCE && tid < NT * 16) rsum[tid] = 0.f;

  const int ocl = lane & 15;
  const int kg  = lane >> 4;

  vf4 acc2[2][NT];
  #pragma unroll
  for (int nt = 0; nt < NT; nt++) {
    float bv = bia[og * NT * 16 + nt * 16 + ocl];
    #pragma unroll
    for (int mt = 0; mt < 2; mt++) {
      vf4 c; c[0] = bv; c[1] = bv; c[2] = bv; c[3] = bv;
      acc2[mt][nt] = c;
    }
  }

  vbf8 bw[9 * NT];

  for (int kc = 0; kc < KC; kc++) {
    if (kc) __syncthreads();
    for (int i = tid; i < 33 * 33 * NG; i += 512) {
      int g = i & (NG - 1);
      int pp = i / NG;
      int yy = pp / 33, xx = pp - yy * 33;
      int gy = iy0 + yy, gx = ix0 + xx;
      vbf8 v = {0, 0, 0, 0, 0, 0, 0, 0};
      if ((unsigned)gy < (unsigned)HIN && (unsigned)gx < (unsigned)HIN)
        v = *(const vbf8*)(inb + (size_t)(gy * HIN + gx) * CIN + kc * 32 + g * 8);
      const int par = xx & 1, hx = xx >> 1;
      const int f = (hx >> FS) & (NG - 1);
      *(vbf8*)(&h1p[par][yy][hx][(g ^ f) * 8]) = v;
    }
    {
      const u16* wfb = g_wfrag + wfo + lane * 8;
      #pragma unroll
      for (int t = 0; t < 9; t++)
        #pragma unroll
        for (int nt = 0; nt < NT; nt++)
          bw[t * NT + nt] =
              *(const vbf8*)(wfb + (size_t)((kc * 9 + t) * NTF + og * NT + nt) * 512);
    }
    __syncthreads();

    #pragma unroll
    for (int t = 0; t < 9; t++) {
      const int ty = t / 3, tx = t % 3;
      const int par = tx & 1;
      const int hx = (lane & 15) + (tx >> 1);
      const int f = (hx >> FS) & (NG - 1);
      #pragma unroll
      for (int mt = 0; mt < 2; mt++) {
        const int y = 2 * (wv * 2 + mt) + ty;
        const u16* ap;
        if constexpr (NG == 4) {
          ap = &h1p[par][y][hx][((kg ^ f) & 3) * 8];
        } else {
          ap = (kg < NG) ? &h1p[par][y][hx][((kg ^ f) & (NG - 1)) * 8] : zbuf;
        }
        vbf8 a = *(const vbf8*)ap;
        #pragma unroll
        for (int nt = 0; nt < NT; nt++)
          acc2[mt][nt] = __builtin_amdgcn_mfma_f32_16x16x32_bf16(
              a, bw[t * NT + nt], acc2[mt][nt], 0, 0, 0);
      }
    }
  }

  if constexpr (REDUCE) {
    #pragma unroll
    for (int nt = 0; nt < NT; nt++) {
      float part = 0.f;
      #pragma unroll
      for (int mt = 0; mt < 2; mt++)
        #pragma unroll
        for (int j = 0; j < 4; j++)
          part += fmaxf(acc2[mt][nt][j], 0.f);
      atomicAdd(&rsum[nt * 16 + ocl], part);
    }
    __syncthreads();
    if (tid < NT * 16)
      atomicAdd(&g_state[gofs + zb2 * COUT + og * NT * 16 + tid],
                rsum[tid] * (1.f / 16384.f));
  } else {
    #pragma unroll
    for (int mt = 0; mt < 2; mt++) {
      const int oy = oy0 + wv * 2 + mt;
      #pragma unroll
      for (int nt = 0; nt < NT; nt++) {
        const int oc = og * NT * 16 + nt * 16 + ocl;
        #pragma unroll
        for (int j = 0; j < 4; j++) {
          const int ox = ox0 + kg * 4 + j;
          out[((size_t)zb2 * HO * HO + (size_t)(oy * HO + ox)) * COUT + oc] =
              f2b(fmaxf(acc2[mt][nt][j], 0.f));
        }
      }
    }
  }
}

// ---------- FC head ----------
template<int CF, int NOUT, bool SIG>
__global__ __launch_bounds__(256) void khead(
    const float* __restrict__ fw1, const float* __restrict__ fb1,
    const float* __restrict__ fw2, const float* __restrict__ fb2,
    int feato, int outo, float* out_f)
{
  __shared__ float fc1[4 * CF];
  const int tid = threadIdx.x;
  if (tid < 4 * CF) {
    int b = tid / CF, o = tid - b * CF;
    float s = fb1[o];
    for (int i = 0; i < CF; i++)
      s = fmaf(g_state[feato + b * CF + i], fw1[o * CF + i], s);
    fc1[tid] = fmaxf(s, 0.f);
  }
  __syncthreads();
  if (tid < 4 * NOUT) {
    int b = tid / NOUT, n = tid - b * NOUT;
    float s = fb2[n];
    for (int i = 0; i < CF; i++)
      s = fmaf(fc1[b * CF + i], fw2[n * CF + i], s);
    if (SIG) s = 1.f / (1.f + expf(-s));
    g_state[outo + b * NOUT + n] = s;
    if (out_f) out_f[b * NOUT + n] = s;
  }
}

// ---------- fused LUT = clip(w3d @ luts + identity, 0,1); also fp16 AoS copy ----------
__global__ __launch_bounds__(256) void kfuse(
    const float* __restrict__ luts, float* __restrict__ outF,
    u16* __restrict__ Fa)
{
  if (blockIdx.x == 0 && threadIdx.x == 0) {
    g_state[GS_ACCS] = 0.f; g_state[GS_ACCS + 1] = 0.f;
  }
  int idx = blockIdx.x * 256 + threadIdx.x;
  if (idx >= 431244) return;
  int n = idx / 107811, m = idx - n * 107811;
  int c = m / 35937, q = m - c * 35937;
  int bq = q / 1089, r2 = q - bq * 1089;
  int gq = r2 / 33, rq = r2 - gq * 33;
  int id = (c == 0) ? rq : (c == 1) ? gq : bq;
  float s = (float)id * (1.f / 32.f);
  #pragma unroll
  for (int k = 0; k < 8; k++)
    s = fmaf(g_state[GS_W3D + n * 8 + k], luts[k * 107811 + m], s);
  s = fminf(fmaxf(s, 0.f), 1.f);
  outF[idx] = s;
  if (Fa) Fa[(n * 35937 + q) * 4 + c] = f2h(s);
}

// ---------- TV + monotonicity reductions over fused ----------
__global__ __launch_bounds__(256) void ktv(const float* __restrict__ f) {
  const int Nr = 418176;
  float tv = 0.f, mn = 0.f;
  for (int e = blockIdx.x * 256 + threadIdx.x; e < 3 * Nr; e += gridDim.x * 256) {
    int dir = e / Nr, j = e - dir * Nr;
    int i, stride; float w;
    if (dir == 0) {
      int r = j & 31; int t = j >> 5;
      int g = t % 33; t /= 33;
      i = t * 1089 + g * 33 + r; stride = 1;
      w = (r == 0 || r == 31) ? 2.f : 1.f;
    } else if (dir == 1) {
      int r = j % 33; int t = j / 33; int g = t & 31; t >>= 5;
      i = t * 1089 + g * 33 + r; stride = 33;
      w = (g == 0 || g == 31) ? 2.f : 1.f;
    } else {
      int r = j % 33; int t = j / 33; int g = t % 33; t /= 33;
      int bb = t & 31; t >>= 5;
      i = (t * 33 + bb) * 1089 + g * 33 + r; stride = 1089;
      w = (bb == 0 || bb == 31) ? 2.f : 1.f;
    }
    float d = f[i] - f[i + stride];
    tv = fmaf(d * d, w, tv);
    mn += fmaxf(d, 0.f);
  }
  __shared__ float r1[256], r2[256];
  r1[threadIdx.x] = tv; r2[threadIdx.x] = mn; __syncthreads();
  for (int st = 128; st > 0; st >>= 1) {
    if (threadIdx.x < st) { r1[threadIdx.x] += r1[threadIdx.x + st];
                            r2[threadIdx.x] += r2[threadIdx.x + st]; }
    __syncthreads();
  }
  if (threadIdx.x == 0) {
    atomicAdd(&g_state[GS_ACCS], r1[0]);
    atomicAdd(&g_state[GS_ACCS + 1], r2[0]);
  }
}

// ---------- trilinear apply, 4 px/thread, fp16 AoS LUT ----------
__global__ __launch_bounds__(256) void kapply4(
    const float* __restrict__ x, const u16* __restrict__ Fa,
    float* __restrict__ out)
{
  int p = blockIdx.x * 256 + threadIdx.x;   // grid 4096
  if (p == 0) {
    out[OUT_TV] = g_state[GS_ACCS] * (1.f / 418176.f);
    out[OUT_MN] = g_state[GS_ACCS + 1] * (1.f / 418176.f);
  }
  const int b = p >> 18;
  const int yx0 = (p & 262143) * 4;
  const size_t base = (size_t)b * 3145728u + yx0;
  vf4 xr = *(const vf4*)(x + base);
  vf4 xg = *(const vf4*)(x + base + 1048576);
  vf4 xb = *(const vf4*)(x + base + 2097152);
  const float a = g_state[GS_BLEND + b];
  const u32* Fu = (const u32*)Fa;

  int cb4[4];
  float fr4[4], fg4[4], fb4[4];
  #pragma unroll
  for (int i = 0; i < 4; i++) {
    float sr = fminf(fmaxf(xr[i], 0.f), 1.f) * 32.f;
    float sg = fminf(fmaxf(xg[i], 0.f), 1.f) * 32.f;
    float sb = fminf(fmaxf(xb[i], 0.f), 1.f) * 32.f;
    int ir = min((int)sr, 31), ig = min((int)sg, 31), ib = min((int)sb, 31);
    fr4[i] = sr - ir; fg4[i] = sg - ig; fb4[i] = sb - ib;
    cb4[i] = b * 35937 + ib * 1089 + ig * 33 + ir;
  }

  // 16 independent dwordx4 gathers
  u32 q[4][4][4];
  const int off[4] = {0, 33, 1089, 1122};
  #pragma unroll
  for (int i = 0; i < 4; i++)
    #pragma unroll
    for (int pr = 0; pr < 4; pr++) {
      const u32* c0 = Fu + (size_t)(cb4[i] + off[pr]) * 2;
      q[i][pr][0] = c0[0]; q[i][pr][1] = c0[1];
      q[i][pr][2] = c0[2]; q[i][pr][3] = c0[3];
    }

  vf4 o0, o1, o2;
  #pragma unroll
  for (int i = 0; i < 4; i++) {
    const float fr = fr4[i], fg = fg4[i], fb = fb4[i];
    #pragma unroll
    for (int c = 0; c < 3; c++) {
      const int k = c >> 1, sh = (c & 1) * 16;
      float v000 = h2f((u16)(q[i][0][k]     >> sh));
      float v001 = h2f((u16)(q[i][0][2 + k] >> sh));
      float v010 = h2f((u16)(q[i][1][k]     >> sh));
      float v011 = h2f((u16)(q[i][1][2 + k] >> sh));
      float v100 = h2f((u16)(q[i][2][k]     >> sh));
      float v101 = h2f((u16)(q[i][2][2 + k] >> sh));
      float v110 = h2f((u16)(q[i][3][k]     >> sh));
      float v111 = h2f((u16)(q[i][3][2 + k] >> sh));
      float c00 = v000 + fr * (v001 - v000);
      float c01 = v010 + fr * (v011 - v010);
      float c10 = v100 + fr * (v101 - v100);
      float c11 = v110 + fr * (v111 - v110);
      float c0 = c00 + fg * (c01 - c00);
      float c1 = c10 + fg * (c11 - c10);
      float v  = c0 + fb * (c1 - c0);
      float xv = (c == 0) ? xr[i] : (c == 1) ? xg[i] : xb[i];
      float o = fminf(fmaxf((1.f - a) * xv + a * v, 0.f), 1.f);
      if (c == 0) o0[i] = o; else if (c == 1) o1[i] = o; else o2[i] = o;
    }
  }
  *(vf4*)(out + (size_t)(b * 3 + 0) * 1048576u + yx0) = o0;
  *(vf4*)(out + (size_t)(b * 3 + 1) * 1048576u + yx0) = o1;
  *(vf4*)(out + (size_t)(b * 3 + 2) * 1048576u + yx0) = o2;
}

// ---------- trilinear apply, fallback 1 px/thread, fp32 SoA ----------
__global__ __launch_bounds__(256) void kapply1(
    const float* __restrict__ x, const float* __restrict__ F,
    float* __restrict__ out)
{
  int p = blockIdx.x * 256 + threadIdx.x;
  if (p == 0) {
    out[OUT_TV] = g_state[GS_ACCS] * (1.f / 418176.f);
    out[OUT_MN] = g_state[GS_ACCS + 1] * (1.f / 418176.f);
  }
  int b = p >> 20, yx = p & 1048575;
  size_t base = (size_t)b * 3145728u + yx;
  float xr = x[base];
  float xg = x[base + 1048576];
  float xb = x[base + 2097152];
  float a = g_state[GS_BLEND + b];
  float sr = fminf(fmaxf(xr, 0.f), 1.f) * 32.f;
  float sg = fminf(fmaxf(xg, 0.f), 1.f) * 32.f;
  float sb = fminf(fmaxf(xb, 0.f), 1.f) * 32.f;
  int ir = min((int)sr, 31), ig = min((int)sg, 31), ib = min((int)sb, 31);
  float fr = sr - ir, fg = sg - ig, fb = sb - ib;
  const float* Fb = F + (size_t)b * 107811u + ib * 1089 + ig * 33 + ir;
  #pragma unroll
  for (int c = 0; c < 3; c++) {
    const float* Fc = Fb + c * 35937;
    float v000 = Fc[0],    v001 = Fc[1];
    float v010 = Fc[33],   v011 = Fc[34];
    float v100 = Fc[1089], v101 = Fc[1090];
    float v110 = Fc[1122], v111 = Fc[1123];
    float c00 = v000 + fr * (v001 - v000);
    float c01 = v010 + fr * (v011 - v010);
    float c10 = v100 + fr * (v101 - v100);
    float c11 = v110 + fr * (v111 - v110);
    float c0 = c00 + fg * (c01 - c00);
    float c1 = c10 + fg * (c11 - c10);
    float v  = c0 + fb * (c1 - c0);
    float xv = (c == 0) ? xr : (c == 1) ? xg : xb;
    float o = fminf(fmaxf((1.f - a) * xv + a * v, 0.f), 1.f);
    out[(size_t)(b * 3 + c) * 1048576u + yx] = o;
  }
}

extern "C" void kernel_launch(void* const* d_in, const int* in_sizes, int n_in,
                              void* d_out, int out_size, void* d_ws, size_t ws_size,
                              hipStream_t stream)
{
  (void)in_sizes; (void)n_in; (void)out_size;
  const float* x    = (const float*)d_in[0];
  const float* luts = (const float*)d_in[1];
  const float* wn_b1 = (const float*)d_in[3];
  const float* wn_b2 = (const float*)d_in[5];
  const float* wn_b3 = (const float*)d_in[7];
  const float* wn_b4 = (const float*)d_in[9];
  const float* wn_fw1 = (const float*)d_in[10], *wn_fb1 = (const float*)d_in[11];
  const float* wn_fw2 = (const float*)d_in[12], *wn_fb2 = (const float*)d_in[13];
  const float* bl_b1 = (const float*)d_in[15];
  const float* bl_b2 = (const float*)d_in[17];
  const float* bl_b3 = (const float*)d_in[19];
  const float* bl_b4 = (const float*)d_in[21];
  const float* bl_fw1 = (const float*)d_in[22], *bl_fb1 = (const float*)d_in[23];
  const float* bl_fw2 = (const float*)d_in[24], *bl_fb2 = (const float*)d_in[25];
  float* out = (float*)d_out;
  const bool hasWs = (ws_size >= 50331648u);

  P2Args p2;
  const float* wsrc[8] = {(const float*)d_in[4],  (const float*)d_in[16],
                          (const float*)d_in[6],  (const float*)d_in[8],
                          (const float*)d_in[18], (const float*)d_in[20],
                          (const float*)d_in[2],  (const float*)d_in[14]};
  const int pI[8]   = {32, 16, 32, 64, 16, 32, 3, 3};
  const int pNTF[8] = {2, 1, 4, 4, 2, 2, 2, 1};
  const int pB[8]   = {WF_WN2, WF_BL2, WF_WN3, WF_WN4, WF_BL3, WF_BL4,
                       WF_WN1, WF_BL1};
  for (int l = 0; l < 8; l++) { p2.w[l] = wsrc[l]; p2.I[l] = pI[l];
                                p2.ntf[l] = pNTF[l]; p2.base[l] = pB[l]; }
  kprep2<<<dim3(348), 256, 0, stream>>>(p2);

  if (hasWs) {
    u16* scrA = (u16*)d_ws;                    // WN h2: 33.6 MB
    u16* scrB = (u16*)d_ws + 16777216;         // conv3 out: up to 16.8 MB
    u16* blh2 = (u16*)out;                     // BL h2: 16.8 MB (out scratch)
    u16* Fa   = (u16*)d_ws;                    // fp16 AoS LUT (post-conv)

    for (int b0 = 0; b0 < 4; b0 += 2) {
      const float* xb = x + (size_t)b0 * 3145728u;
      k12d<<<dim3(32,32,2), 512, 0, stream>>>(xb, wn_b1, wn_b2, bl_b1, bl_b2,
                                              scrA, blh2);
      k34m<32,64,2,4,1,false><<<dim3(16,16,4), 512, 0, stream>>>(scrA, wn_b3, WF_WN3, scrB, 512, 0);
      k34m<64,64,2,4,2,true ><<<dim3(8,8,4),   512, 0, stream>>>(scrB, wn_b4, WF_WN4, nullptr, 256, GS_FEATWN + b0 * 64);
      k34m<16,32,2,2,1,false><<<dim3(16,16,2), 512, 0, stream>>>(blh2, bl_b3, WF_BL3, scrB, 512, 0);
      k34m<32,32,2,4,1,true ><<<dim3(8,8,2),   512, 0, stream>>>(scrB, bl_b4, WF_BL4, nullptr, 256, GS_FEATBL + b0 * 32);
    }
    khead<64,8,false><<<1,256,0,stream>>>(wn_fw1, wn_fb1, wn_fw2, wn_fb2,
                                          GS_FEATWN, GS_W3D, out + OUT_W3D);
    khead<32,1,true ><<<1,256,0,stream>>>(bl_fw1, bl_fb1, bl_fw2, bl_fb2,
                                          GS_FEATBL, GS_BLEND, (float*)nullptr);

    kfuse<<<1685, 256, 0, stream>>>(luts, out + OUT_FUSED, Fa);
    ktv<<<512, 256, 0, stream>>>(out + OUT_FUSED);
    kapply4<<<4096, 256, 0, stream>>>(x, Fa, out);
  } else {
    u16* scrA = (u16*)out;
    u16* scrB = (u16*)out + 16777216;

    for (int b0 = 0; b0 < 4; b0 += 2) {
      const float* xb = x + (size_t)b0 * 3145728u;
      k12m<32,32,2,4><<<dim3(32,32,2), 512, 0, stream>>>(xb, WF_WN1, wn_b1, wn_b2, WF_WN2, scrA);
      k34m<32,64,2,4,1,false><<<dim3(16,16,4), 512, 0, stream>>>(scrA, wn_b3, WF_WN3, scrB, 512, 0);
      k34m<64,64,2,4,2,true ><<<dim3(8,8,4),   512, 0, stream>>>(scrB, wn_b4, WF_WN4, nullptr, 256, GS_FEATWN + b0 * 64);
    }
    khead<64,8,false><<<1,256,0,stream>>>(wn_fw1, wn_fb1, wn_fw2, wn_fb2,
                                          GS_FEATWN, GS_W3D, out + OUT_W3D);
    for (int b0 = 0; b0 < 4; b0 += 2) {
      const float* xb = x + (size_t)b0 * 3145728u;
      k12m<16,16,1,2><<<dim3(32,32,2), 512, 0, stream>>>(xb, WF_BL1, bl_b1, bl_b2, WF_BL2, scrA);
      k34m<16,32,2,2,1,false><<<dim3(16,16,2), 512, 0, stream>>>(scrA, bl_b3, WF_BL3, scrB, 512, 0);
      k34m<32,32,2,4,1,true ><<<dim3(8,8,2),   512, 0, stream>>>(scrB, bl_b4, WF_BL4, nullptr, 256, GS_FEATBL + b0 * 32);
    }
    khead<32,1,true ><<<1,256,0,stream>>>(bl_fw1, bl_fb1, bl_fw2, bl_fb2,
                                          GS_FEATBL, GS_BLEND, (float*)nullptr);

    kfuse<<<1685, 256, 0, stream>>>(luts, out + OUT_FUSED, nullptr);
    ktv<<<512, 256, 0, stream>>>(out + OUT_FUSED);
    kapply1<<<16384, 256, 0, stream>>>(x, out + OUT_FUSED, out);
  }
}

// Round 6
// 486.547 us; speedup vs baseline: 3.6558x; 1.0078x over previous
//
#include <hip/hip_runtime.h>

typedef unsigned short u16;
typedef unsigned int u32;
typedef __attribute__((ext_vector_type(8))) short vbf8;   // 8 bf16 = 4 VGPR
typedef __attribute__((ext_vector_type(4))) short vs4;    // 4 bf16 = 8 B
typedef __attribute__((ext_vector_type(4))) float vf4;    // MFMA acc / float4

// ---------- bf16 <-> f32 (bitwise; RNE on pack) ----------
__device__ __forceinline__ float b2f(u16 u) {
  union { unsigned int i; float f; } v; v.i = ((unsigned int)u) << 16; return v.f;
}
__device__ __forceinline__ u16 f2b(float f) {
  union { float f; unsigned int i; } v; v.f = f;
  unsigned int r = v.i + 0x7fffu + ((v.i >> 16) & 1u);
  return (u16)(r >> 16);
}
__device__ __forceinline__ u16 f2h(float f) {
  union { _Float16 h; u16 s; } cv; cv.h = (_Float16)f; return cv.s;
}
__device__ __forceinline__ float h2f(u16 u) {
  union { _Float16 h; u16 s; } cv; cv.s = u; return (float)cv.h;
}

// ---------- tiny cross-kernel state ------
__device__ float g_state[512];
#define GS_FEATWN 0      // 256
#define GS_FEATBL 256    // 128
#define GS_W3D    384    // 32
#define GS_BLEND  416    // 4
#define GS_ACCS   420    // 2

// ---------- MFMA-fragment-ordered bf16 conv weights ----------
// conv2..4 frag (kc,t,nt): 64 lanes x 8 bf16;
//   elem (l,j) = W[oc=nt*16+(l&15)][ic=kc*32+(l>>4)*8+j][t]; idx = (kc*9+t)*NTF+nt
// conv1 v2 frag (g,mt): elem (l,j) = W[oc=mt*16+(l&15)][ic=j][tap=g*4+(l>>4)],
//   zero when j>=3 or tap>=9 ; frag idx = g*MT1 + mt (3 groups)
__device__ __align__(16) u16 g_wfrag[92160];
#define WF_WN2 0       // NTF=2 KC=1 : 18 frags
#define WF_BL2 9216    // NTF=1 KC=1 :  9
#define WF_WN3 13824   // NTF=4 KC=1 : 36
#define WF_WN4 32256   // NTF=4 KC=2 : 72
#define WF_BL3 69120   // NTF=2 KC=1 : 18 (I=16 zero-pad)
#define WF_BL4 78336   // NTF=2 KC=1 : 18
#define WF_WN1 87552   // conv1 v2: 3 groups x 2 mt = 6 frags
#define WF_BL1 90624   // conv1 v2: 3 groups x 1 mt = 3 frags

// ---------- output layout (fp32 elements) ----------
#define OUT_FUSED 12582912
#define OUT_TV    13014156
#define OUT_MN    13014157
#define OUT_W3D   13014158

// ---------- prep: pack all conv weights into MFMA fragment order ----------
struct P2Args { const float* w[8]; int I[8]; int ntf[8]; int base[8]; };

__global__ __launch_bounds__(256) void kprep2(P2Args a) {
  if (blockIdx.x == 0 && threadIdx.x < 256) {
    g_state[threadIdx.x] = 0.f;
    if (threadIdx.x < 128) g_state[256 + threadIdx.x] = 0.f;
  }
  int i = blockIdx.x * 256 + threadIdx.x;   // grid 360*256 = 92160 exact
  int l = 0;
  #pragma unroll
  for (int k = 1; k < 8; k++) if (i >= a.base[k]) l = k;
  int e2 = i - a.base[l];
  int frag = e2 >> 9, e = e2 & 511;
  int ll = e >> 3, j = e & 7;
  if (l < 6) {
    int NTF = a.ntf[l];
    int kc = frag / (9 * NTF);
    int r = frag - kc * 9 * NTF;
    int t = r / NTF, nt = r - t * NTF;
    int I = a.I[l];
    int oc = nt * 16 + (ll & 15);
    int ic = kc * 32 + (ll >> 4) * 8 + j;
    g_wfrag[i] = (ic < I) ? f2b(a.w[l][(oc * I + ic) * 9 + t]) : (u16)0;
  } else {
    // conv1 v2: tap-group layout
    int isWN = (l == 6);
    int g = isWN ? (frag >> 1) : frag;
    int mt = isWN ? (frag & 1) : 0;
    int tap = g * 4 + (ll >> 4);
    int oc = mt * 16 + (ll & 15);
    g_wfrag[i] = (j < 3 && tap < 9) ? f2b(a.w[l][oc * 27 + j * 9 + tap]) : (u16)0;
  }
}

// ---------- merged WN+BL conv1+conv2 (ws path), 512 threads ----------
// x staged once as NHWC [35][36][8]; conv1 B-frags (3x ds_read_b128) shared
// between WN and BL; both h1 buffers resident (74 KB LDS, 2 blk/CU).
__global__ __launch_bounds__(512) void k12d(
    const float* __restrict__ x,
    const float* __restrict__ wb1, const float* __restrict__ wb2,
    const float* __restrict__ bb1, const float* __restrict__ bb2,
    u16* __restrict__ h2w, u16* __restrict__ h2b)
{
  __shared__ __align__(16) u16 xs[10080];      // 35*36*8 = 20,160 B
  __shared__ __align__(16) u16 h1w[35904];     // 2*33*17*32
  __shared__ __align__(16) u16 h1b[17952];     // 2*33*17*16
  __shared__ __align__(16) u16 zbuf[8];
  const int tid = threadIdx.x;
  const int lane = tid & 63, wv = tid >> 6;
  const int ocl = lane & 15;
  const int kg  = lane >> 4;
  const int oy0 = blockIdx.y * 16, ox0 = blockIdx.x * 16;
  const int hy0 = 2 * oy0 - 1, hx0 = 2 * ox0 - 1;
  const float* xb = x + (size_t)blockIdx.z * 3145728u;
  u16* h2wb = h2w + (size_t)blockIdx.z * 262144u * 32u;
  u16* h2bb = h2b + (size_t)blockIdx.z * 262144u * 16u;

  if (tid < 8) zbuf[tid] = 0;
  // ---- stage x NHWC ----
  for (int i = tid; i < 1225; i += 512) {
    int yy = i / 35, xx = i - yy * 35;
    int gy = hy0 - 1 + yy, gx = hx0 - 1 + xx;
    vbf8 v = {0, 0, 0, 0, 0, 0, 0, 0};
    if ((unsigned)gy < 1024u && (unsigned)gx < 1024u) {
      const float* pp = xb + (gy << 10) + gx;
      v[0] = (short)f2b(pp[0]);
      v[1] = (short)f2b(pp[1048576]);
      v[2] = (short)f2b(pp[2097152]);
    }
    *(vbf8*)(&xs[(yy * 36 + xx) * 8]) = v;
  }

  // per-lane tap-group byte offsets (clamped for pad taps; weights are 0 there)
  int tgo[3];
  #pragma unroll
  for (int g = 0; g < 3; g++) {
    int tap = g * 4 + kg; if (tap > 8) tap = 8;
    tgo[g] = ((tap / 3) * 36 + (tap % 3)) * 16;   // bytes
  }

  // conv1 weight frags + biases
  vbf8 waW[6], waB[3];
  float bias1[2][4], bias1b[4];
  {
    const u16* wfb = g_wfrag + lane * 8;
    #pragma unroll
    for (int q = 0; q < 6; q++) waW[q] = *(const vbf8*)(wfb + WF_WN1 + q * 512);
    #pragma unroll
    for (int g = 0; g < 3; g++) waB[g] = *(const vbf8*)(wfb + WF_BL1 + g * 512);
    #pragma unroll
    for (int j = 0; j < 4; j++) {
      bias1[0][j] = wb1[kg * 4 + j];
      bias1[1][j] = wb1[16 + kg * 4 + j];
      bias1b[j]   = bb1[kg * 4 + j];
    }
  }
  __syncthreads();

  // ---- conv1 (both nets, shared B-frags) ----
  for (int pt = wv; pt < 69; pt += 8) {
    const int p = pt * 16 + ocl;
    const bool ok = (p < 1089);
    const int pc = ok ? p : 1088;
    const int py = pc / 33, px = pc - py * 33;
    const char* pb = (const char*)&xs[(py * 36 + px) * 8];
    vbf8 bf[3];
    #pragma unroll
    for (int g = 0; g < 3; g++)
      bf[g] = *(const vbf8*)(pb + tgo[g]);
    const int par = px & 1, hx = px >> 1;
    // WN
    {
      const int f = (hx >> 1) & 3;
      const int hb = ((par * 33 + py) * 17 + hx) * 32;
      #pragma unroll
      for (int mt = 0; mt < 2; mt++) {
        vf4 acc = {0.f, 0.f, 0.f, 0.f};
        #pragma unroll
        for (int g = 0; g < 3; g++)
          acc = __builtin_amdgcn_mfma_f32_16x16x32_bf16(waW[g * 2 + mt], bf[g], acc, 0, 0, 0);
        if (ok) {
          vs4 pk;
          #pragma unroll
          for (int j = 0; j < 4; j++)
            pk[j] = (short)f2b(fmaxf(acc[j] + bias1[mt][j], 0.f));
          const int q = kg + 4 * mt;
          *(vs4*)(&h1w[hb + ((q >> 1) ^ f) * 8 + (q & 1) * 4]) = pk;
        }
      }
    }
    // BL
    {
      const int f = (hx >> 2) & 1;
      vf4 acc = {0.f, 0.f, 0.f, 0.f};
      #pragma unroll
      for (int g = 0; g < 3; g++)
        acc = __builtin_amdgcn_mfma_f32_16x16x32_bf16(waB[g], bf[g], acc, 0, 0, 0);
      if (ok) {
        vs4 pk;
        #pragma unroll
        for (int j = 0; j < 4; j++)
          pk[j] = (short)f2b(fmaxf(acc[j] + bias1b[j], 0.f));
        *(vs4*)(&h1b[((par * 33 + py) * 17 + hx) * 16 + ((kg >> 1) ^ f) * 8 + (kg & 1) * 4]) = pk;
      }
    }
  }
  __syncthreads();

  // ---- conv2 WN (NT=2, NG=4) ----
  {
    vbf8 bw[18];
    const u16* wfb = g_wfrag + WF_WN2 + lane * 8;
    #pragma unroll
    for (int i = 0; i < 18; i++)
      bw[i] = *(const vbf8*)(wfb + i * 512);

    vf4 acc2[2][2];
    #pragma unroll
    for (int nt = 0; nt < 2; nt++) {
      float bv = wb2[nt * 16 + ocl];
      #pragma unroll
      for (int mt = 0; mt < 2; mt++) {
        vf4 c; c[0] = bv; c[1] = bv; c[2] = bv; c[3] = bv;
        acc2[mt][nt] = c;
      }
    }
    #pragma unroll
    for (int t = 0; t < 9; t++) {
      const int ty = t / 3, tx = t % 3;
      const int par = tx & 1;
      const int hx = (lane & 15) + (tx >> 1);
      const int f = (hx >> 1) & 3;
      #pragma unroll
      for (int mt = 0; mt < 2; mt++) {
        const int y = 2 * (wv * 2 + mt) + ty;
        vbf8 a = *(const vbf8*)(&h1w[((par * 33 + y) * 17 + hx) * 32 + ((kg ^ f) & 3) * 8]);
        #pragma unroll
        for (int nt = 0; nt < 2; nt++)
          acc2[mt][nt] = __builtin_amdgcn_mfma_f32_16x16x32_bf16(
              a, bw[t * 2 + nt], acc2[mt][nt], 0, 0, 0);
      }
    }
    #pragma unroll
    for (int mt = 0; mt < 2; mt++) {
      const int oy = oy0 + wv * 2 + mt;
      #pragma unroll
      for (int nt = 0; nt < 2; nt++)
        #pragma unroll
        for (int j = 0; j < 4; j++) {
          const int ox = ox0 + kg * 4 + j;
          h2wb[((size_t)(oy << 9) + ox) * 32 + nt * 16 + ocl] =
              f2b(fmaxf(acc2[mt][nt][j], 0.f));
        }
    }
  }

  // ---- conv2 BL (NT=1, NG=2) ----
  {
    vbf8 bw[9];
    const u16* wfb = g_wfrag + WF_BL2 + lane * 8;
    #pragma unroll
    for (int i = 0; i < 9; i++)
      bw[i] = *(const vbf8*)(wfb + i * 512);

    vf4 acc2[2];
    {
      float bv = bb2[ocl];
      #pragma unroll
      for (int mt = 0; mt < 2; mt++) {
        vf4 c; c[0] = bv; c[1] = bv; c[2] = bv; c[3] = bv;
        acc2[mt] = c;
      }
    }
    #pragma unroll
    for (int t = 0; t < 9; t++) {
      const int ty = t / 3, tx = t % 3;
      const int par = tx & 1;
      const int hx = (lane & 15) + (tx >> 1);
      const int f = (hx >> 2) & 1;
      #pragma unroll
      for (int mt = 0; mt < 2; mt++) {
        const int y = 2 * (wv * 2 + mt) + ty;
        const u16* ap = (kg < 2)
            ? &h1b[((par * 33 + y) * 17 + hx) * 16 + ((kg ^ f) & 1) * 8]
            : zbuf;
        vbf8 a = *(const vbf8*)ap;
        acc2[mt] = __builtin_amdgcn_mfma_f32_16x16x32_bf16(
            a, bw[t], acc2[mt], 0, 0, 0);
      }
    }
    #pragma unroll
    for (int mt = 0; mt < 2; mt++) {
      const int oy = oy0 + wv * 2 + mt;
      #pragma unroll
      for (int j = 0; j < 4; j++) {
        const int ox = ox0 + kg * 4 + j;
        h2bb[((size_t)(oy << 9) + ox) * 16 + ocl] =
            f2b(fmaxf(acc2[mt][j], 0.f));
      }
    }
  }
}

// ---------- separate conv1+conv2 (fallback path), 512 threads, v2 conv1 ----------
template<int C1, int C2, int NT, int NG>
__global__ __launch_bounds__(512) void k12m(
    const float* __restrict__ x, int wf1o, const float* __restrict__ b1,
    const float* __restrict__ b2, int wfo, u16* __restrict__ h2)
{
  constexpr int FS = (NG == 4) ? 1 : 2;
  constexpr int MT1 = C1 / 16;
  __shared__ __align__(16) u16 xs[10080];
  __shared__ __align__(16) u16 h1p[2][33][17][C1];
  __shared__ __align__(16) u16 zbuf[8];
  const int tid = threadIdx.x;
  const int lane = tid & 63, wv = tid >> 6;
  const int ocl = lane & 15;
  const int kg  = lane >> 4;
  const int oy0 = blockIdx.y * 16, ox0 = blockIdx.x * 16;
  const int hy0 = 2 * oy0 - 1, hx0 = 2 * ox0 - 1;
  const float* xb = x + (size_t)blockIdx.z * 3145728u;
  u16* h2b = h2 + (size_t)blockIdx.z * 262144u * (size_t)C2;

  if (tid < 8) zbuf[tid] = 0;
  for (int i = tid; i < 1225; i += 512) {
    int yy = i / 35, xx = i - yy * 35;
    int gy = hy0 - 1 + yy, gx = hx0 - 1 + xx;
    vbf8 v = {0, 0, 0, 0, 0, 0, 0, 0};
    if ((unsigned)gy < 1024u && (unsigned)gx < 1024u) {
      const float* pp = xb + (gy << 10) + gx;
      v[0] = (short)f2b(pp[0]);
      v[1] = (short)f2b(pp[1048576]);
      v[2] = (short)f2b(pp[2097152]);
    }
    *(vbf8*)(&xs[(yy * 36 + xx) * 8]) = v;
  }

  int tgo[3];
  #pragma unroll
  for (int g = 0; g < 3; g++) {
    int tap = g * 4 + kg; if (tap > 8) tap = 8;
    tgo[g] = ((tap / 3) * 36 + (tap % 3)) * 16;
  }

  vbf8 wa1[3 * MT1];
  float bias1[MT1][4];
  {
    const u16* wfb = g_wfrag + wf1o + lane * 8;
    #pragma unroll
    for (int q = 0; q < 3 * MT1; q++)
      wa1[q] = *(const vbf8*)(wfb + q * 512);
    #pragma unroll
    for (int mt = 0; mt < MT1; mt++)
      #pragma unroll
      for (int j = 0; j < 4; j++)
        bias1[mt][j] = b1[mt * 16 + kg * 4 + j];
  }
  __syncthreads();

  for (int pt = wv; pt < 69; pt += 8) {
    const int p = pt * 16 + ocl;
    const bool ok = (p < 1089);
    const int pc = ok ? p : 1088;
    const int py = pc / 33, px = pc - py * 33;
    const char* pb = (const char*)&xs[(py * 36 + px) * 8];
    vbf8 bf[3];
    #pragma unroll
    for (int g = 0; g < 3; g++)
      bf[g] = *(const vbf8*)(pb + tgo[g]);
    const int par = px & 1, hx = px >> 1;
    const int f = (hx >> FS) & (NG - 1);
    #pragma unroll
    for (int mt = 0; mt < MT1; mt++) {
      vf4 acc = {0.f, 0.f, 0.f, 0.f};
      #pragma unroll
      for (int g = 0; g < 3; g++)
        acc = __builtin_amdgcn_mfma_f32_16x16x32_bf16(wa1[g * MT1 + mt], bf[g], acc, 0, 0, 0);
      if (ok) {
        vs4 pk;
        #pragma unroll
        for (int j = 0; j < 4; j++)
          pk[j] = (short)f2b(fmaxf(acc[j] + bias1[mt][j], 0.f));
        const int q = kg + 4 * mt;
        *(vs4*)(&h1p[par][py][hx][((q >> 1) ^ f) * 8 + (q & 1) * 4]) = pk;
      }
    }
  }
  __syncthreads();

  vbf8 bw[9 * NT];
  {
    const u16* wfb = g_wfrag + wfo + lane * 8;
    #pragma unroll
    for (int i = 0; i < 9 * NT; i++)
      bw[i] = *(const vbf8*)(wfb + i * 512);
  }

  vf4 acc2[2][NT];
  #pragma unroll
  for (int nt = 0; nt < NT; nt++) {
    float bv = b2[nt * 16 + ocl];
    #pragma unroll
    for (int mt = 0; mt < 2; mt++) {
      vf4 c; c[0] = bv; c[1] = bv; c[2] = bv; c[3] = bv;
      acc2[mt][nt] = c;
    }
  }

  #pragma unroll
  for (int t = 0; t < 9; t++) {
    const int ty = t / 3, tx = t % 3;
    const int par = tx & 1;
    const int hx = (lane & 15) + (tx >> 1);
    const int f = (hx >> FS) & (NG - 1);
    #pragma unroll
    for (int mt = 0; mt < 2; mt++) {
      const int y = 2 * (wv * 2 + mt) + ty;
      const u16* ap;
      if constexpr (NG == 4) {
        ap = &h1p[par][y][hx][((kg ^ f) & 3) * 8];
      } else {
        ap = (kg < NG) ? &h1p[par][y][hx][((kg ^ f) & (NG - 1)) * 8] : zbuf;
      }
      vbf8 a = *(const vbf8*)ap;
      #pragma unroll
      for (int nt = 0; nt < NT; nt++)
        acc2[mt][nt] = __builtin_amdgcn_mfma_f32_16x16x32_bf16(
            a, bw[t * NT + nt], acc2[mt][nt], 0, 0, 0);
    }
  }

  #pragma unroll
  for (int mt = 0; mt < 2; mt++) {
    const int oy = oy0 + wv * 2 + mt;
    #pragma unroll
    for (int nt = 0; nt < NT; nt++) {
      #pragma unroll
      for (int j = 0; j < 4; j++) {
        const int ox = ox0 + kg * 4 + j;
        h2b[((size_t)(oy << 9) + ox) * C2 + nt * 16 + ocl] =
            f2b(fmaxf(acc2[mt][nt][j], 0.f));
      }
    }
  }
}

// ---------- stride-2 conv on MFMA (conv3/conv4), NHWC in, 512 threads ----------
template<int CIN, int COUT, int NT, int NG, int KC, bool REDUCE>
__global__ __launch_bounds__(512) void k34m(
    const u16* __restrict__ in, const float* __restrict__ bia,
    int wfo, u16* __restrict__ out, int HIN, int gofs)
{
  constexpr int FS = (NG == 4) ? 1 : 2;
  constexpr int NTF = COUT / 16;
  constexpr int OCG = COUT / (NT * 16);
  __shared__ __align__(16) u16 h1p[2][33][17][NG * 8];
  __shared__ __align__(16) u16 zbuf[8];
  __shared__ float rsum[NT * 16];
  const int HO = HIN >> 1;
  const int tid = threadIdx.x;
  const int lane = tid & 63, wv = tid >> 6;
  const int zb2 = blockIdx.z / OCG;
  const int og = blockIdx.z - zb2 * OCG;
  const int oy0 = blockIdx.y * 16, ox0 = blockIdx.x * 16;
  const int iy0 = 2 * oy0 - 1, ix0 = 2 * ox0 - 1;
  const u16* inb = in + (size_t)zb2 * (size_t)HIN * HIN * CIN;

  if (tid < 8) zbuf[tid] = 0;
  if (REDUCE && tid < NT * 16) rsum[tid] = 0.f;

  const int ocl = lane & 15;
  const int kg  = lane >> 4;

  vf4 acc2[2][NT];
  #pragma unroll
  for (int nt = 0; nt < NT; nt++) {
    float bv = bia[og * NT * 16 + nt * 16 + ocl];
    #pragma unroll
    for (int mt = 0; mt < 2; mt++) {
      vf4 c; c[0] = bv; c[1] = bv; c[2] = bv; c[3] = bv;
      acc2[mt][nt] = c;
    }
  }

  vbf8 bw[9 * NT];

  for (int kc = 0; kc < KC; kc++) {
    if (kc) __syncthreads();
    for (int i = tid; i < 33 * 33 * NG; i += 512) {
      int g = i & (NG - 1);
      int pp = i / NG;
      int yy = pp / 33, xx = pp - yy * 33;
      int gy = iy0 + yy, gx = ix0 + xx;
      vbf8 v = {0, 0, 0, 0, 0, 0, 0, 0};
      if ((unsigned)gy < (unsigned)HIN && (unsigned)gx < (unsigned)HIN)
        v = *(const vbf8*)(inb + (size_t)(gy * HIN + gx) * CIN + kc * 32 + g * 8);
      const int par = xx & 1, hx = xx >> 1;
      const int f = (hx >> FS) & (NG - 1);
      *(vbf8*)(&h1p[par][yy][hx][(g ^ f) * 8]) = v;
    }
    {
      const u16* wfb = g_wfrag + wfo + lane * 8;
      #pragma unroll
      for (int t = 0; t < 9; t++)
        #pragma unroll
        for (int nt = 0; nt < NT; nt++)
          bw[t * NT + nt] =
              *(const vbf8*)(wfb + (size_t)((kc * 9 + t) * NTF + og * NT + nt) * 512);
    }
    __syncthreads();

    #pragma unroll
    for (int t = 0; t < 9; t++) {
      const int ty = t / 3, tx = t % 3;
      const int par = tx & 1;
      const int hx = (lane & 15) + (tx >> 1);
      const int f = (hx >> FS) & (NG - 1);
      #pragma unroll
      for (int mt = 0; mt < 2; mt++) {
        const int y = 2 * (wv * 2 + mt) + ty;
        const u16* ap;
        if constexpr (NG == 4) {
          ap = &h1p[par][y][hx][((kg ^ f) & 3) * 8];
        } else {
          ap = (kg < NG) ? &h1p[par][y][hx][((kg ^ f) & (NG - 1)) * 8] : zbuf;
        }
        vbf8 a = *(const vbf8*)ap;
        #pragma unroll
        for (int nt = 0; nt < NT; nt++)
          acc2[mt][nt] = __builtin_amdgcn_mfma_f32_16x16x32_bf16(
              a, bw[t * NT + nt], acc2[mt][nt], 0, 0, 0);
      }
    }
  }

  if constexpr (REDUCE) {
    #pragma unroll
    for (int nt = 0; nt < NT; nt++) {
      float part = 0.f;
      #pragma unroll
      for (int mt = 0; mt < 2; mt++)
        #pragma unroll
        for (int j = 0; j < 4; j++)
          part += fmaxf(acc2[mt][nt][j], 0.f);
      atomicAdd(&rsum[nt * 16 + ocl], part);
    }
    __syncthreads();
    if (tid < NT * 16)
      atomicAdd(&g_state[gofs + zb2 * COUT + og * NT * 16 + tid],
                rsum[tid] * (1.f / 16384.f));
  } else {
    #pragma unroll
    for (int mt = 0; mt < 2; mt++) {
      const int oy = oy0 + wv * 2 + mt;
      #pragma unroll
      for (int nt = 0; nt < NT; nt++) {
        const int oc = og * NT * 16 + nt * 16 + ocl;
        #pragma unroll
        for (int j = 0; j < 4; j++) {
          const int ox = ox0 + kg * 4 + j;
          out[((size_t)zb2 * HO * HO + (size_t)(oy * HO + ox)) * COUT + oc] =
              f2b(fmaxf(acc2[mt][nt][j], 0.f));
        }
      }
    }
  }
}

// ---------- FC head ----------
template<int CF, int NOUT, bool SIG>
__global__ __launch_bounds__(256) void khead(
    const float* __restrict__ fw1, const float* __restrict__ fb1,
    const float* __restrict__ fw2, const float* __restrict__ fb2,
    int feato, int outo, float* out_f)
{
  __shared__ float fc1[4 * CF];
  const int tid = threadIdx.x;
  if (tid < 4 * CF) {
    int b = tid / CF, o = tid - b * CF;
    float s = fb1[o];
    for (int i = 0; i < CF; i++)
      s = fmaf(g_state[feato + b * CF + i], fw1[o * CF + i], s);
    fc1[tid] = fmaxf(s, 0.f);
  }
  __syncthreads();
  if (tid < 4 * NOUT) {
    int b = tid / NOUT, n = tid - b * NOUT;
    float s = fb2[n];
    for (int i = 0; i < CF; i++)
      s = fmaf(fc1[b * CF + i], fw2[n * CF + i], s);
    if (SIG) s = 1.f / (1.f + expf(-s));
    g_state[outo + b * NOUT + n] = s;
    if (out_f) out_f[b * NOUT + n] = s;
  }
}

// ---------- fused LUT = clip(w3d @ luts + identity, 0,1); also fp16 AoS copy ----------
__global__ __launch_bounds__(256) void kfuse(
    const float* __restrict__ luts, float* __restrict__ outF,
    u16* __restrict__ Fa)
{
  if (blockIdx.x == 0 && threadIdx.x == 0) {
    g_state[GS_ACCS] = 0.f; g_state[GS_ACCS + 1] = 0.f;
  }
  int idx = blockIdx.x * 256 + threadIdx.x;
  if (idx >= 431244) return;
  int n = idx / 107811, m = idx - n * 107811;
  int c = m / 35937, q = m - c * 35937;
  int bq = q / 1089, r2 = q - bq * 1089;
  int gq = r2 / 33, rq = r2 - gq * 33;
  int id = (c == 0) ? rq : (c == 1) ? gq : bq;
  float s = (float)id * (1.f / 32.f);
  #pragma unroll
  for (int k = 0; k < 8; k++)
    s = fmaf(g_state[GS_W3D + n * 8 + k], luts[k * 107811 + m], s);
  s = fminf(fmaxf(s, 0.f), 1.f);
  outF[idx] = s;
  if (Fa) Fa[(n * 35937 + q) * 4 + c] = f2h(s);
}

// ---------- TV + monotonicity reductions over fused ----------
__global__ __launch_bounds__(256) void ktv(const float* __restrict__ f) {
  const int Nr = 418176;
  float tv = 0.f, mn = 0.f;
  for (int e = blockIdx.x * 256 + threadIdx.x; e < 3 * Nr; e += gridDim.x * 256) {
    int dir = e / Nr, j = e - dir * Nr;
    int i, stride; float w;
    if (dir == 0) {
      int r = j & 31; int t = j >> 5;
      int g = t % 33; t /= 33;
      i = t * 1089 + g * 33 + r; stride = 1;
      w = (r == 0 || r == 31) ? 2.f : 1.f;
    } else if (dir == 1) {
      int r = j % 33; int t = j / 33; int g = t & 31; t >>= 5;
      i = t * 1089 + g * 33 + r; stride = 33;
      w = (g == 0 || g == 31) ? 2.f : 1.f;
    } else {
      int r = j % 33; int t = j / 33; int g = t % 33; t /= 33;
      int bb = t & 31; t >>= 5;
      i = (t * 33 + bb) * 1089 + g * 33 + r; stride = 1089;
      w = (bb == 0 || bb == 31) ? 2.f : 1.f;
    }
    float d = f[i] - f[i + stride];
    tv = fmaf(d * d, w, tv);
    mn += fmaxf(d, 0.f);
  }
  __shared__ float r1[256], r2[256];
  r1[threadIdx.x] = tv; r2[threadIdx.x] = mn; __syncthreads();
  for (int st = 128; st > 0; st >>= 1) {
    if (threadIdx.x < st) { r1[threadIdx.x] += r1[threadIdx.x + st];
                            r2[threadIdx.x] += r2[threadIdx.x + st]; }
    __syncthreads();
  }
  if (threadIdx.x == 0) {
    atomicAdd(&g_state[GS_ACCS], r1[0]);
    atomicAdd(&g_state[GS_ACCS + 1], r2[0]);
  }
}

// ---------- trilinear apply, 4 px/thread, fp16 AoS LUT ----------
__global__ __launch_bounds__(256) void kapply4(
    const float* __restrict__ x, const u16* __restrict__ Fa,
    float* __restrict__ out)
{
  int p = blockIdx.x * 256 + threadIdx.x;   // grid 4096
  if (p == 0) {
    out[OUT_TV] = g_state[GS_ACCS] * (1.f / 418176.f);
    out[OUT_MN] = g_state[GS_ACCS + 1] * (1.f / 418176.f);
  }
  const int b = p >> 18;
  const int yx0 = (p & 262143) * 4;
  const size_t base = (size_t)b * 3145728u + yx0;
  vf4 xr = *(const vf4*)(x + base);
  vf4 xg = *(const vf4*)(x + base + 1048576);
  vf4 xb = *(const vf4*)(x + base + 2097152);
  const float a = g_state[GS_BLEND + b];
  const u32* Fu = (const u32*)Fa;

  int cb4[4];
  float fr4[4], fg4[4], fb4[4];
  #pragma unroll
  for (int i = 0; i < 4; i++) {
    float sr = fminf(fmaxf(xr[i], 0.f), 1.f) * 32.f;
    float sg = fminf(fmaxf(xg[i], 0.f), 1.f) * 32.f;
    float sb = fminf(fmaxf(xb[i], 0.f), 1.f) * 32.f;
    int ir = min((int)sr, 31), ig = min((int)sg, 31), ib = min((int)sb, 31);
    fr4[i] = sr - ir; fg4[i] = sg - ig; fb4[i] = sb - ib;
    cb4[i] = b * 35937 + ib * 1089 + ig * 33 + ir;
  }

  u32 q[4][4][4];
  const int off[4] = {0, 33, 1089, 1122};
  #pragma unroll
  for (int i = 0; i < 4; i++)
    #pragma unroll
    for (int pr = 0; pr < 4; pr++) {
      const u32* c0 = Fu + (size_t)(cb4[i] + off[pr]) * 2;
      q[i][pr][0] = c0[0]; q[i][pr][1] = c0[1];
      q[i][pr][2] = c0[2]; q[i][pr][3] = c0[3];
    }

  vf4 o0, o1, o2;
  #pragma unroll
  for (int i = 0; i < 4; i++) {
    const float fr = fr4[i], fg = fg4[i], fb = fb4[i];
    #pragma unroll
    for (int c = 0; c < 3; c++) {
      const int k = c >> 1, sh = (c & 1) * 16;
      float v000 = h2f((u16)(q[i][0][k]     >> sh));
      float v001 = h2f((u16)(q[i][0][2 + k] >> sh));
      float v010 = h2f((u16)(q[i][1][k]     >> sh));
      float v011 = h2f((u16)(q[i][1][2 + k] >> sh));
      float v100 = h2f((u16)(q[i][2][k]     >> sh));
      float v101 = h2f((u16)(q[i][2][2 + k] >> sh));
      float v110 = h2f((u16)(q[i][3][k]     >> sh));
      float v111 = h2f((u16)(q[i][3][2 + k] >> sh));
      float c00 = v000 + fr * (v001 - v000);
      float c01 = v010 + fr * (v011 - v010);
      float c10 = v100 + fr * (v101 - v100);
      float c11 = v110 + fr * (v111 - v110);
      float c0 = c00 + fg * (c01 - c00);
      float c1 = c10 + fg * (c11 - c10);
      float v  = c0 + fb * (c1 - c0);
      float xv = (c == 0) ? xr[i] : (c == 1) ? xg[i] : xb[i];
      float o = fminf(fmaxf((1.f - a) * xv + a * v, 0.f), 1.f);
      if (c == 0) o0[i] = o; else if (c == 1) o1[i] = o; else o2[i] = o;
    }
  }
  *(vf4*)(out + (size_t)(b * 3 + 0) * 1048576u + yx0) = o0;
  *(vf4*)(out + (size_t)(b * 3 + 1) * 1048576u + yx0) = o1;
  *(vf4*)(out + (size_t)(b * 3 + 2) * 1048576u + yx0) = o2;
}

// ---------- trilinear apply, fallback 1 px/thread, fp32 SoA ----------
__global__ __launch_bounds__(256) void kapply1(
    const float* __restrict__ x, const float* __restrict__ F,
    float* __restrict__ out)
{
  int p = blockIdx.x * 256 + threadIdx.x;
  if (p == 0) {
    out[OUT_TV] = g_state[GS_ACCS] * (1.f / 418176.f);
    out[OUT_MN] = g_state[GS_ACCS + 1] * (1.f / 418176.f);
  }
  int b = p >> 20, yx = p & 1048575;
  size_t base = (size_t)b * 3145728u + yx;
  float xr = x[base];
  float xg = x[base + 1048576];
  float xb = x[base + 2097152];
  float a = g_state[GS_BLEND + b];
  float sr = fminf(fmaxf(xr, 0.f), 1.f) * 32.f;
  float sg = fminf(fmaxf(xg, 0.f), 1.f) * 32.f;
  float sb = fminf(fmaxf(xb, 0.f), 1.f) * 32.f;
  int ir = min((int)sr, 31), ig = min((int)sg, 31), ib = min((int)sb, 31);
  float fr = sr - ir, fg = sg - ig, fb = sb - ib;
  const float* Fb = F + (size_t)b * 107811u + ib * 1089 + ig * 33 + ir;
  #pragma unroll
  for (int c = 0; c < 3; c++) {
    const float* Fc = Fb + c * 35937;
    float v000 = Fc[0],    v001 = Fc[1];
    float v010 = Fc[33],   v011 = Fc[34];
    float v100 = Fc[1089], v101 = Fc[1090];
    float v110 = Fc[1122], v111 = Fc[1123];
    float c00 = v000 + fr * (v001 - v000);
    float c01 = v010 + fr * (v011 - v010);
    float c10 = v100 + fr * (v101 - v100);
    float c11 = v110 + fr * (v111 - v110);
    float c0 = c00 + fg * (c01 - c00);
    float c1 = c10 + fg * (c11 - c10);
    float v  = c0 + fb * (c1 - c0);
    float xv = (c == 0) ? xr : (c == 1) ? xg : xb;
    float o = fminf(fmaxf((1.f - a) * xv + a * v, 0.f), 1.f);
    out[(size_t)(b * 3 + c) * 1048576u + yx] = o;
  }
}

extern "C" void kernel_launch(void* const* d_in, const int* in_sizes, int n_in,
                              void* d_out, int out_size, void* d_ws, size_t ws_size,
                              hipStream_t stream)
{
  (void)in_sizes; (void)n_in; (void)out_size;
  const float* x    = (const float*)d_in[0];
  const float* luts = (const float*)d_in[1];
  const float* wn_b1 = (const float*)d_in[3];
  const float* wn_b2 = (const float*)d_in[5];
  const float* wn_b3 = (const float*)d_in[7];
  const float* wn_b4 = (const float*)d_in[9];
  const float* wn_fw1 = (const float*)d_in[10], *wn_fb1 = (const float*)d_in[11];
  const float* wn_fw2 = (const float*)d_in[12], *wn_fb2 = (const float*)d_in[13];
  const float* bl_b1 = (const float*)d_in[15];
  const float* bl_b2 = (const float*)d_in[17];
  const float* bl_b3 = (const float*)d_in[19];
  const float* bl_b4 = (const float*)d_in[21];
  const float* bl_fw1 = (const float*)d_in[22], *bl_fb1 = (const float*)d_in[23];
  const float* bl_fw2 = (const float*)d_in[24], *bl_fb2 = (const float*)d_in[25];
  float* out = (float*)d_out;
  const bool hasWs = (ws_size >= 50331648u);

  P2Args p2;
  const float* wsrc[8] = {(const float*)d_in[4],  (const float*)d_in[16],
                          (const float*)d_in[6],  (const float*)d_in[8],
                          (const float*)d_in[18], (const float*)d_in[20],
                          (const float*)d_in[2],  (const float*)d_in[14]};
  const int pI[8]   = {32, 16, 32, 64, 16, 32, 3, 3};
  const int pNTF[8] = {2, 1, 4, 4, 2, 2, 2, 1};
  const int pB[8]   = {WF_WN2, WF_BL2, WF_WN3, WF_WN4, WF_BL3, WF_BL4,
                       WF_WN1, WF_BL1};
  for (int l = 0; l < 8; l++) { p2.w[l] = wsrc[l]; p2.I[l] = pI[l];
                                p2.ntf[l] = pNTF[l]; p2.base[l] = pB[l]; }
  kprep2<<<dim3(360), 256, 0, stream>>>(p2);

  if (hasWs) {
    u16* scrA = (u16*)d_ws;                    // WN h2: 33.6 MB
    u16* scrB = (u16*)d_ws + 16777216;         // conv3 out: up to 16.8 MB
    u16* blh2 = (u16*)out;                     // BL h2: 16.8 MB (out scratch)
    u16* Fa   = (u16*)d_ws;                    // fp16 AoS LUT (post-conv)

    for (int b0 = 0; b0 < 4; b0 += 2) {
      const float* xb = x + (size_t)b0 * 3145728u;
      k12d<<<dim3(32,32,2), 512, 0, stream>>>(xb, wn_b1, wn_b2, bl_b1, bl_b2,
                                              scrA, blh2);
      k34m<32,64,2,4,1,false><<<dim3(16,16,4), 512, 0, stream>>>(scrA, wn_b3, WF_WN3, scrB, 512, 0);
      k34m<64,64,2,4,2,true ><<<dim3(8,8,4),   512, 0, stream>>>(scrB, wn_b4, WF_WN4, nullptr, 256, GS_FEATWN + b0 * 64);
      k34m<16,32,2,2,1,false><<<dim3(16,16,2), 512, 0, stream>>>(blh2, bl_b3, WF_BL3, scrB, 512, 0);
      k34m<32,32,2,4,1,true ><<<dim3(8,8,2),   512, 0, stream>>>(scrB, bl_b4, WF_BL4, nullptr, 256, GS_FEATBL + b0 * 32);
    }
    khead<64,8,false><<<1,256,0,stream>>>(wn_fw1, wn_fb1, wn_fw2, wn_fb2,
                                          GS_FEATWN, GS_W3D, out + OUT_W3D);
    khead<32,1,true ><<<1,256,0,stream>>>(bl_fw1, bl_fb1, bl_fw2, bl_fb2,
                                          GS_FEATBL, GS_BLEND, (float*)nullptr);

    kfuse<<<1685, 256, 0, stream>>>(luts, out + OUT_FUSED, Fa);
    ktv<<<512, 256, 0, stream>>>(out + OUT_FUSED);
    kapply4<<<4096, 256, 0, stream>>>(x, Fa, out);
  } else {
    u16* scrA = (u16*)out;
    u16* scrB = (u16*)out + 16777216;

    for (int b0 = 0; b0 < 4; b0 += 2) {
      const float* xb = x + (size_t)b0 * 3145728u;
      k12m<32,32,2,4><<<dim3(32,32,2), 512, 0, stream>>>(xb, WF_WN1, wn_b1, wn_b2, WF_WN2, scrA);
      k34m<32,64,2,4,1,false><<<dim3(16,16,4), 512, 0, stream>>>(scrA, wn_b3, WF_WN3, scrB, 512, 0);
      k34m<64,64,2,4,2,true ><<<dim3(8,8,4),   512, 0, stream>>>(scrB, wn_b4, WF_WN4, nullptr, 256, GS_FEATWN + b0 * 64);
    }
    khead<64,8,false><<<1,256,0,stream>>>(wn_fw1, wn_fb1, wn_fw2, wn_fb2,
                                          GS_FEATWN, GS_W3D, out + OUT_W3D);
    for (int b0 = 0; b0 < 4; b0 += 2) {
      const float* xb = x + (size_t)b0 * 3145728u;
      k12m<16,16,1,2><<<dim3(32,32,2), 512, 0, stream>>>(xb, WF_BL1, bl_b1, bl_b2, WF_BL2, scrA);
      k34m<16,32,2,2,1,false><<<dim3(16,16,2), 512, 0, stream>>>(scrA, bl_b3, WF_BL3, scrB, 512, 0);
      k34m<32,32,2,4,1,true ><<<dim3(8,8,2),   512, 0, stream>>>(scrB, bl_b4, WF_BL4, nullptr, 256, GS_FEATBL + b0 * 32);
    }
    khead<32,1,true ><<<1,256,0,stream>>>(bl_fw1, bl_fb1, bl_fw2, bl_fb2,
                                          GS_FEATBL, GS_BLEND, (float*)nullptr);

    kfuse<<<1685, 256, 0, stream>>>(luts, out + OUT_FUSED, nullptr);
    ktv<<<512, 256, 0, stream>>>(out + OUT_FUSED);
    kapply1<<<16384, 256, 0, stream>>>(x, out + OUT_FUSED, out);
  }
}